// Round 14
// baseline (314.182 us; speedup 1.0000x reference)
//
#include <hip/hip_runtime.h>

// VectorQuantiser forward, MI355X fp32.
// N=65536 tokens (16x64x64, channel dim 64 strided by 4096), K=1024 codes, D=64.
//
// Round 16. Round-15 regression root-caused: merging the latency-bound
// col-rescore (scattered z gathers, needs 8 waves/SIMD) with the register-
// blocked row-rescore (acc[16][4] -> VGPR 108) in ONE kernel halved the col
// part's occupancy (13% measured) -> 168us. VGPR budget is per-kernel;
// incompatible profiles must not share a launch. Fix: split.
//  - k_colres: verbatim round-14 col body, launch_bounds(256), VGPR ~50.
//  - k_rowres: round-15 register-blocked row body (16x fewer z loads),
//    grid (64,16), launch_bounds(256,2); its 108 VGPR is now harmless.
// k_prep / k_mfma (incl. staging swizzle) / k_tokens / k_tail byte-identical
// to round 15. All exact fp paths verbatim; absmax must stay 1.525879e-05.

#define MARGIN 2e-4f
#define CERT   2e-4f

// ---- ws layout (bytes) ----
#define WS_ROW   0         // u64 wsrow[65536]
#define WS_COL   524288    // u64 wscol[1024]
#define WS_CNT   532480    // u32 counts[1024]
#define WS_LOSS  536576    // double loss_acc
#define WS_EN2   536592    // float en2[1024]
#define WS_LCNT  540688    // u32 lcnt
#define WS_ZN2   541696    // float zn2[65536]            (256KB)
#define WS_EBH   803840    // u16 ebf_hi[1024*64]         (128KB)
#define WS_EBL   934912    // u16 ebf_lo[1024*64]         (128KB)
#define WS_LIST  1065984   // u32 list[65536]             (256KB)
#define WS_CBM   1328128   // f32 colbm[1024][512]        (2MB)
#define WS_BYTES 3425280
#define WS_ZERO  540720    // memset range: row/col/cnt/loss/lcnt

typedef __attribute__((ext_vector_type(8))) short short8v;
typedef __attribute__((ext_vector_type(4))) float f32x4;

__device__ __forceinline__ unsigned int f32_ord(float x) {
    unsigned int b = __float_as_uint(x);
    return (b & 0x80000000u) ? ~b : (b | 0x80000000u);
}
__device__ __forceinline__ float ord_f32(unsigned int u) {  // exact inverse
    unsigned int b = (u & 0x80000000u) ? (u & 0x7FFFFFFFu) : ~u;
    return __uint_as_float(b);
}

__device__ __forceinline__ unsigned short f2bf(float f) {  // RNE fp32->bf16
    unsigned int u = __float_as_uint(f);
    return (unsigned short)((u + 0x7FFFu + ((u >> 16) & 1u)) >> 16);
}
__device__ __forceinline__ float bf2f(unsigned short h) {
    return __uint_as_float((unsigned int)h << 16);
}

// numpy pairwise sum of squares over 64 values (verbatim from passing code).
template <typename F>
__device__ __forceinline__ float np_pairwise64_sq(F get) {
    float r[8];
#pragma unroll
    for (int j = 0; j < 8; ++j) {
        float v = get(j);
        r[j] = __fmul_rn(v, v);
    }
#pragma unroll
    for (int i = 8; i < 64; i += 8) {
#pragma unroll
        for (int j = 0; j < 8; ++j) {
            float v = get(i + j);
            r[j] = __fadd_rn(r[j], __fmul_rn(v, v));
        }
    }
    return __fadd_rn(__fadd_rn(__fadd_rn(r[0], r[1]), __fadd_rn(r[2], r[3])),
                     __fadd_rn(__fadd_rn(r[4], r[5]), __fadd_rn(r[6], r[7])));
}

// ---- K0: e-only prep: en2 + codebook bf16 hi/lo splits (4 blocks) ----
__global__ __launch_bounds__(256) void k_prep(
    const float* __restrict__ emb, float* __restrict__ en2,
    unsigned int* __restrict__ ebh32, unsigned int* __restrict__ ebl32) {
    const int t = threadIdx.x;
    const int k = blockIdx.x * 256 + t;
    const float* a = emb + (size_t)k * 64;
    float ar[64];
#pragma unroll
    for (int i = 0; i < 64; ++i) ar[i] = a[i];
    en2[k] = np_pairwise64_sq([&](int i) { return ar[i]; });
#pragma unroll
    for (int wd = 0; wd < 32; ++wd) {
        float e0 = ar[2 * wd], e1 = ar[2 * wd + 1];
        unsigned short h0 = f2bf(e0), h1 = f2bf(e1);
        ebh32[k * 32 + wd] = (unsigned int)h0 | ((unsigned int)h1 << 16);
        unsigned short l0 = f2bf(__fsub_rn(e0, bf2f(h0)));
        unsigned short l1 = f2bf(__fsub_rn(e1, bf2f(h1)));
        ebl32[k * 32 + wd] = (unsigned int)l0 | ((unsigned int)l1 << 16);
    }
}

// ---- K1: fused z-prep + s~ via bf16 MFMA + top-2 certification ----
// (byte-identical to round 15)
__global__ __launch_bounds__(512, 2) void k_mfma(
    const float* __restrict__ z,
    const unsigned short* __restrict__ ebh, const unsigned short* __restrict__ ebl,
    float* __restrict__ zn2, const float* __restrict__ en2,
    float* __restrict__ cbm, unsigned long long* __restrict__ wsrow,
    unsigned int* __restrict__ lcnt, unsigned int* __restrict__ list) {
    const int t = threadIdx.x, l = t & 63, w = t >> 6;
    const int n0 = blockIdx.x * 128;
    const int tw = n0 + w * 16;
    const int lm = l & 15, kg = l >> 4;
    const int b   = n0 >> 12;
    const int hw0 = n0 & 4095;

    __shared__ __align__(16) unsigned char smem[45056];
    unsigned int* eh   = (unsigned int*)(smem);            // [2][64*36]
    unsigned int* el   = (unsigned int*)(smem + 18432);    // [2][64*36]
    float*        en2l = (float*)(smem + 36864);           // [1024]
    unsigned int* cmU  = (unsigned int*)(smem + 40960);    // [1024]
    float*        zl   = (float*)(smem);                   // [64][129] prologue
    float*        zntmp= (float*)(smem + 36864);           // [128]     prologue

    // --- prologue phase 1: global z -> LDS transpose (coalesced) ---
    const float* zsrc = z + (size_t)b * 262144 + hw0;
#pragma unroll
    for (int it = 0; it < 16; ++it) {
        int idx = it * 512 + t;
        int c = idx >> 7, tok = idx & 127;
        zl[c * 129 + tok] = zsrc[(size_t)c * 4096 + tok];
    }
    __syncthreads();

    // --- prologue phase 2: zn2 (verbatim chain) + fragment assembly ---
    if (t < 128) {
        float v = np_pairwise64_sq([&](int i) { return zl[i * 129 + t]; });
        zn2[n0 + t] = v;
        zntmp[t] = v;
    }
    const int tokA = w * 16 + lm;   // block-local token of this thread's A-frag
    short8v ah0, ah1, al0, al1;
#pragma unroll
    for (int j = 0; j < 8; ++j) {
        float z0 = zl[(kg * 8 + j) * 129 + tokA];
        float z1 = zl[(32 + kg * 8 + j) * 129 + tokA];
        unsigned short h0 = f2bf(z0);
        unsigned short h1 = f2bf(z1);
        ah0[j] = (short)h0;
        ah1[j] = (short)h1;
        al0[j] = (short)f2bf(__fsub_rn(z0, bf2f(h0)));
        al1[j] = (short)f2bf(__fsub_rn(z1, bf2f(h1)));
    }
    __syncthreads();

    // --- prologue phase 3: read zn2 for this thread's C/D rows ---
    float nzn2[4];
#pragma unroll
    for (int j = 0; j < 4; ++j) nzn2[j] = -zntmp[w * 16 + kg * 4 + j];
    __syncthreads();

    // --- prologue phase 4: init en2l/cmU, stage e group 0 ---
    // Staging swizzle: word=(t&7)^(scode&7) -> conflict-free ds_write_b128;
    // global source rotates identically; LDS layout unchanged (reads fine).
    for (int i = t; i < 1024; i += 512) { en2l[i] = en2[i]; cmU[i] = 0u; }
    const uint4* EH4 = reinterpret_cast<const uint4*>(ebh);
    const uint4* EL4 = reinterpret_cast<const uint4*>(ebl);
    const int scode = t >> 3;
    const int sword = (t & 7) ^ (scode & 7);
    const int swd   = sword * 4;
    const int sidx  = scode * 8 + sword;
    {
        uint4 hv = EH4[sidx], lv = EL4[sidx];
        *reinterpret_cast<uint4*>(&eh[0 * 2304 + scode * 36 + swd]) = hv;
        *reinterpret_cast<uint4*>(&el[0 * 2304 + scode * 36 + swd]) = lv;
    }

    float v1[4] = {-3.4e38f, -3.4e38f, -3.4e38f, -3.4e38f};
    float v2[4] = {-3.4e38f, -3.4e38f, -3.4e38f, -3.4e38f};
    int   c1[4] = {0, 0, 0, 0};

    __syncthreads();

    for (int g = 0; g < 16; ++g) {
        const int buf = g & 1;
        const bool pf = (g < 15);
        uint4 hv, lv;
        if (pf) {   // issue next group's loads early; write AFTER compute
            hv = EH4[(g + 1) * 512 + sidx];
            lv = EL4[(g + 1) * 512 + sidx];
        }

#pragma unroll
        for (int sc = 0; sc < 4; ++sc) {
            const int cl = sc * 16 + lm;
            const short8v bh0 = *reinterpret_cast<const short8v*>(&eh[buf * 2304 + cl * 36 + kg * 4]);
            const short8v bh1 = *reinterpret_cast<const short8v*>(&eh[buf * 2304 + cl * 36 + 16 + kg * 4]);
            const short8v bl0 = *reinterpret_cast<const short8v*>(&el[buf * 2304 + cl * 36 + kg * 4]);
            const short8v bl1 = *reinterpret_cast<const short8v*>(&el[buf * 2304 + cl * 36 + 16 + kg * 4]);

            f32x4 a1 = {0.f, 0.f, 0.f, 0.f};
            f32x4 a2 = {0.f, 0.f, 0.f, 0.f};
            __builtin_amdgcn_s_setprio(1);
            a1 = __builtin_amdgcn_mfma_f32_16x16x32_bf16(ah0, bh0, a1, 0, 0, 0);
            a1 = __builtin_amdgcn_mfma_f32_16x16x32_bf16(ah1, bh1, a1, 0, 0, 0);
            a2 = __builtin_amdgcn_mfma_f32_16x16x32_bf16(ah0, bl0, a2, 0, 0, 0);
            a2 = __builtin_amdgcn_mfma_f32_16x16x32_bf16(ah1, bl1, a2, 0, 0, 0);
            a2 = __builtin_amdgcn_mfma_f32_16x16x32_bf16(al0, bh0, a2, 0, 0, 0);
            a2 = __builtin_amdgcn_mfma_f32_16x16x32_bf16(al1, bh1, a2, 0, 0, 0);
            __builtin_amdgcn_s_setprio(0);

            const int code = g * 64 + cl;
            const float en2v = en2l[code];
            float cm = -3.4e38f;
#pragma unroll
            for (int j = 0; j < 4; ++j) {
                float acc  = __fadd_rn(a1[j], a2[j]);
                float base = __fsub_rn(nzn2[j], en2v);
                float s    = fmaf(2.0f, acc, base);
                // top-2, min/max form (identical values to the branchy version)
                bool gt = s > v1[j];
                v2[j] = fmaxf(fminf(s, v1[j]), v2[j]);
                v1[j] = fmaxf(v1[j], s);
                c1[j] = gt ? code : c1[j];
                cm = fmaxf(cm, s);
            }
            cm = fmaxf(cm, __shfl_xor(cm, 16, 64));
            cm = fmaxf(cm, __shfl_xor(cm, 32, 64));
            if (l < 16) atomicMax(&cmU[code], f32_ord(cm));
        }

        if (pf) {
            *reinterpret_cast<uint4*>(&eh[(buf ^ 1) * 2304 + scode * 36 + swd]) = hv;
            *reinterpret_cast<uint4*>(&el[(buf ^ 1) * 2304 + scode * 36 + swd]) = lv;
        }
        __syncthreads();
    }

    // ---- row finalize: merge top-2 across the 16 lm-lanes, certify ----
#pragma unroll
    for (int j = 0; j < 4; ++j) {
        unsigned long long key =
            ((unsigned long long)f32_ord(v1[j]) << 32) |
            (unsigned long long)(unsigned int)(~(unsigned int)c1[j]);
        float w2 = v2[j];
#pragma unroll
        for (int m = 1; m < 16; m <<= 1) {
            unsigned long long ok = __shfl_xor(key, m, 64);
            float ov2 = __shfl_xor(w2, m, 64);
            unsigned long long lk = (key < ok) ? key : ok;   // losing top1
            float lv2 = ord_f32((unsigned int)(lk >> 32));
            w2 = fmaxf(fmaxf(w2, ov2), lv2);
            key = (key > ok) ? key : ok;                      // ties: smaller c
        }
        if (lm == 0) {
            const int tn = tw + kg * 4 + j;
            float v1m = ord_f32((unsigned int)(key >> 32));
            if (__fsub_rn(v1m, w2) > CERT) {
                wsrow[tn] = key;      // certified: provably exact argmax index
            } else {
                unsigned int p = atomicAdd(lcnt, 1u);
                list[p] = (unsigned int)tn;
            }
        }
    }

    for (int code = t; code < 1024; code += 512)
        cbm[(size_t)code * 512 + blockIdx.x] = ord_f32(cmU[code]);
}

// ---- K2a: exact column rescore (own launch: low VGPR, high occupancy) ----
// Body verbatim from the 257.9us-validated round-14 code.
__global__ __launch_bounds__(256) void k_colres(
    const float* __restrict__ z, const float* __restrict__ emb,
    const float* __restrict__ zn2, const float* __restrict__ en2,
    const float* __restrict__ cbm, unsigned long long* __restrict__ wscol) {
    const int k = blockIdx.x, t = threadIdx.x;
    __shared__ float red[256];
    __shared__ int   hlist[512];
    __shared__ int   hcnt;
    float a  = cbm[(size_t)k * 512 + t];
    float b2 = cbm[(size_t)k * 512 + 256 + t];
    red[t] = fmaxf(a, b2);
    if (t == 0) hcnt = 0;
    __syncthreads();
    for (int st = 128; st; st >>= 1) {
        if (t < st) red[t] = fmaxf(red[t], red[t + st]);
        __syncthreads();
    }
    const float thr = red[0] - MARGIN;
    if (a >= thr)  { int p = atomicAdd(&hcnt, 1); hlist[p] = t; }
    if (b2 >= thr) { int p = atomicAdd(&hcnt, 1); hlist[p] = t + 256; }
    __syncthreads();
    const int hc = hcnt;
    const float en2k = en2[k];
    const float4* ek = reinterpret_cast<const float4*>(emb + (size_t)k * 64);

    for (int h = 0; h < hc; ++h) {
        const int g = hlist[h];
        if (t < 128) {
            const int n = g * 128 + t;
            const int b = n >> 12, hw = n & 4095;
            const float* zp = z + (size_t)b * 262144 + hw;
            float c0 = 0.f, c1 = 0.f, c2 = 0.f, c3 = 0.f;
#pragma unroll
            for (int j = 0; j < 16; ++j) {
                float4 e = ek[j];
                c0 = fmaf(e.x, zp[(size_t)(4 * j + 0) * 4096], c0);
                c1 = fmaf(e.y, zp[(size_t)(4 * j + 1) * 4096], c1);
                c2 = fmaf(e.z, zp[(size_t)(4 * j + 2) * 4096], c2);
                c3 = fmaf(e.w, zp[(size_t)(4 * j + 3) * 4096], c3);
            }
            float dot = (c0 + c1) + (c2 + c3);
            float d = __fadd_rn(__fsub_rn(-zn2[n], en2k), 2.0f * dot);
            unsigned long long key =
                ((unsigned long long)f32_ord(d) << 32) |
                (unsigned long long)(unsigned int)(~(unsigned int)n);
#pragma unroll
            for (int m = 1; m < 64; m <<= 1) {
                unsigned long long o = __shfl_xor(key, m, 64);
                if (o > key) key = o;    // ties: larger key = smaller n
            }
            if ((t & 63) == 0) atomicMax(&wscol[k], key);
        }
    }
}

// ---- K2b: exact row rescore (own launch: register-blocked, VGPR-heavy) ----
// grid (64,16): blockIdx.y = 64-code partition, grid-stride over the list.
// 16-code register blocking; per-code chains verbatim (bit-identical).
__global__ __launch_bounds__(256, 2) void k_rowres(
    const float* __restrict__ z, const float* __restrict__ emb,
    const float* __restrict__ zn2, const float* __restrict__ en2,
    const unsigned int* __restrict__ list, const unsigned int* __restrict__ lcnt,
    unsigned long long* __restrict__ wsrow) {
    const int t = threadIdx.x;
    const int k0 = blockIdx.y * 64;
    const unsigned int cnt = *lcnt;
    const float4* E4 = reinterpret_cast<const float4*>(emb);
    for (unsigned int i = blockIdx.x * 256 + t; i < cnt; i += 64 * 256) {
        const int n = (int)list[i];
        const int b = n >> 12, hw = n & 4095;
        const float* zp = z + (size_t)b * 262144 + hw;
        const float nz = -zn2[n];
        unsigned long long best = 0ull;
#pragma unroll 1
        for (int grp = 0; grp < 4; ++grp) {
            const int kb = k0 + grp * 16;
            float acc[16][4];
#pragma unroll
            for (int kk = 0; kk < 16; ++kk) {
                acc[kk][0] = 0.f; acc[kk][1] = 0.f;
                acc[kk][2] = 0.f; acc[kk][3] = 0.f;
            }
#pragma unroll
            for (int j = 0; j < 16; ++j) {
                // z loaded ONCE per j for all 16 codes (was per code)
                float z0 = zp[(size_t)(4 * j + 0) * 4096];
                float z1 = zp[(size_t)(4 * j + 1) * 4096];
                float z2 = zp[(size_t)(4 * j + 2) * 4096];
                float z3 = zp[(size_t)(4 * j + 3) * 4096];
#pragma unroll
                for (int kk = 0; kk < 16; ++kk) {
                    float4 e = E4[(size_t)(kb + kk) * 16 + j]; // s_load
                    acc[kk][0] = fmaf(e.x, z0, acc[kk][0]);
                    acc[kk][1] = fmaf(e.y, z1, acc[kk][1]);
                    acc[kk][2] = fmaf(e.z, z2, acc[kk][2]);
                    acc[kk][3] = fmaf(e.w, z3, acc[kk][3]);
                }
            }
#pragma unroll
            for (int kk = 0; kk < 16; ++kk) {
                float dot = __fadd_rn(__fadd_rn(acc[kk][0], acc[kk][1]),
                                      __fadd_rn(acc[kk][2], acc[kk][3]));
                float d = __fadd_rn(__fsub_rn(nz, en2[kb + kk]), 2.0f * dot);
                unsigned long long key =
                    ((unsigned long long)f32_ord(d) << 32) |
                    (unsigned long long)(unsigned int)(~(unsigned int)(kb + kk));
                if (key > best) best = key;  // ties: larger key = smaller k
            }
        }
        atomicMax(&wsrow[n], best);
    }
}

// ---- K3: per-token outputs, 4-way channel split (1024 blocks) ----
__global__ __launch_bounds__(256) void k_tokens(
    const float* __restrict__ z, const float* __restrict__ emb,
    const unsigned long long* __restrict__ wsrow,
    unsigned int* __restrict__ counts, double* __restrict__ loss_acc,
    float* __restrict__ out_zq, float* __restrict__ out_idx) {
    const int t    = threadIdx.x;
    const int lane = t & 63;
    const int q    = t >> 6;
    const int n    = blockIdx.x * 64 + lane;
    const int b    = n >> 12;
    const int hw   = n & 4095;

    unsigned long long key = wsrow[n];
    int idx = (int)(~(unsigned int)(key & 0xFFFFFFFFull));
    if (q == 0) {
        out_idx[n] = (float)idx;
        atomicAdd(&counts[idx], 1u);
    }

    const float* zp = z + (size_t)b * 262144 + hw;
    float*       op = out_zq + (size_t)b * 262144 + hw;
    const float* ep = emb + (size_t)idx * 64;

    double ls = 0.0;
#pragma unroll
    for (int c = q * 16; c < q * 16 + 16; ++c) {
        float zc   = zp[(size_t)c * 4096];
        float eq   = ep[c];
        float diff = __fsub_rn(eq, zc);              // fl(z_q - zc)
        float sq   = __fmul_rn(diff, diff);
        ls += (double)sq;
        op[(size_t)c * 4096] = __fadd_rn(zc, diff);  // zc + fl(z_q - zc)
    }

    __shared__ double sred[256];
    sred[q * 64 + lane] = ls;
    __syncthreads();
    if (t < 64) {
        sred[t] = (sred[t] + sred[64 + t]) + (sred[128 + t] + sred[192 + t]);
    }
    __syncthreads();
    for (int st = 32; st; st >>= 1) {
        if (t < st) sred[t] += sred[t + st];
        __syncthreads();
    }
    if (t == 0) atomicAdd(loss_acc, sred[0]);
}

// ---- K4: tail — new embedding + scalars (unchanged) ----
__global__ __launch_bounds__(1024) void k_tail(
    const float* __restrict__ z, const float* __restrict__ emb,
    const float* __restrict__ embed_prob,
    const unsigned long long* __restrict__ wscol,
    const unsigned int* __restrict__ counts,
    const double* __restrict__ loss_acc,
    float* __restrict__ out_newemb, float* __restrict__ out_loss,
    float* __restrict__ out_perp, float* __restrict__ out_prob) {
    const int k = blockIdx.x * 16 + (threadIdx.x >> 6);
    const int c = threadIdx.x & 63;

    float avg  = (float)counts[k] * (1.0f / 65536.0f);
    float pnew = __fadd_rn(__fmul_rn(embed_prob[k], 0.99f),
                           __fmul_rn(0.01f, avg));
    float tt = __fdiv_rn(__fmul_rn(__fmul_rn(pnew, 1024.0f), 10.0f), 0.01f);
    float dk = expf(__fsub_rn(-tt, 1e-3f));
    float omd = __fsub_rn(1.0f, dk);

    unsigned long long ck = wscol[k];
    int cn  = (int)(~(unsigned int)(ck & 0xFFFFFFFFull));
    int cb  = cn >> 12;
    int chw = cn & 4095;

    float rf = z[(size_t)cb * 262144 + (size_t)c * 4096 + chw];
    float e  = emb[(size_t)k * 64 + c];
    out_newemb[(size_t)k * 64 + c] =
        __fadd_rn(__fmul_rn(e, omd), __fmul_rn(rf, dk));

    if (blockIdx.x == 0) {
        const int q = threadIdx.x;

        float avg2  = (float)counts[q] * (1.0f / 65536.0f);
        float pnew2 = __fadd_rn(__fmul_rn(embed_prob[q], 0.99f),
                                __fmul_rn(0.01f, avg2));
        out_prob[q] = pnew2;

        float term = __fmul_rn(avg2, logf(__fadd_rn(avg2, 1e-10f)));
        __shared__ double red[1024];
        red[q] = (double)term;
        __syncthreads();
        for (int st = 512; st; st >>= 1) {
            if (q < st) red[q] += red[q + st];
            __syncthreads();
        }
        if (q == 0) {
            float s32 = (float)red[0];
            out_perp[0] = expf(-s32);
            double lm = loss_acc[0] / 4194304.0;
            float  m  = (float)lm;
            out_loss[0] = __fadd_rn(__fmul_rn(0.25f, m), m);  // BETA*m + m
        }
    }
}

extern "C" void kernel_launch(void* const* d_in, const int* in_sizes, int n_in,
                              void* d_out, int out_size, void* d_ws, size_t ws_size,
                              hipStream_t stream) {
    const float* z    = (const float*)d_in[0];   // 16*64*64*64
    const float* emb  = (const float*)d_in[1];   // 1024*64
    const float* prob = (const float*)d_in[2];   // 1024

    float* out        = (float*)d_out;
    float* out_zq     = out;                 // 4194304 floats
    float* out_loss   = out + 4194304;
    float* out_perp   = out + 4194305;
    float* out_newemb = out + 4194306;
    float* out_prob   = out + 4259842;
    float* out_idx    = out + 4260866;

    char* ws = (char*)d_ws;
    unsigned long long* wsrow = (unsigned long long*)(ws + WS_ROW);
    unsigned long long* wscol = (unsigned long long*)(ws + WS_COL);
    unsigned int*       cnts  = (unsigned int*)(ws + WS_CNT);
    double*             lacc  = (double*)(ws + WS_LOSS);
    float*              en2   = (float*)(ws + WS_EN2);
    unsigned int*       lcnt  = (unsigned int*)(ws + WS_LCNT);
    float*              zn2   = (float*)(ws + WS_ZN2);
    unsigned short*     ebh   = (unsigned short*)(ws + WS_EBH);
    unsigned short*     ebl   = (unsigned short*)(ws + WS_EBL);
    unsigned int*       list  = (unsigned int*)(ws + WS_LIST);
    float*              cbm   = (float*)(ws + WS_CBM);

    hipMemsetAsync(d_ws, 0, WS_ZERO, stream);

    hipLaunchKernelGGL(k_prep, dim3(4), dim3(256), 0, stream,
                       emb, en2, (unsigned int*)ebh, (unsigned int*)ebl);
    hipLaunchKernelGGL(k_mfma, dim3(512), dim3(512), 0, stream,
                       z, ebh, ebl, zn2, en2, cbm, wsrow, lcnt, list);
    hipLaunchKernelGGL(k_colres, dim3(1024), dim3(256), 0, stream,
                       z, emb, zn2, en2, cbm, wscol);
    hipLaunchKernelGGL(k_rowres, dim3(64, 16), dim3(256), 0, stream,
                       z, emb, zn2, en2, list, lcnt, wsrow);
    hipLaunchKernelGGL(k_tokens, dim3(1024), dim3(256), 0, stream,
                       z, emb, wsrow, cnts, lacc, out_zq, out_idx);
    hipLaunchKernelGGL(k_tail, dim3(64), dim3(1024), 0, stream,
                       z, emb, prob, wscol, cnts, lacc,
                       out_newemb, out_loss, out_perp, out_prob);
}

// Round 15
// 215.328 us; speedup vs baseline: 1.4591x; 1.4591x over previous
//
#include <hip/hip_runtime.h>

// VectorQuantiser forward, MI355X fp32.
// N=65536 tokens (16x64x64, channel dim 64 strided by 4096), K=1024 codes, D=64.
//
// Round 17. Round-16 lesson: the register-blocked row-rescore (VGPR 108, 4
// waves/SIMD) is strictly worse than the old low-VGPR body (44, 8 waves/SIMD)
// for a latency-bound gather kernel -- TLP beats load-count (same lesson as
// the 32-tok/wave regression, other direction). Also FETCH=25.6MB showed the
// atomic-scrambled list makes every z load a 64-cacheline wave gather.
// Fixes:
//  - k_mfma: block-local list compaction. Uncertified tokens buffered in LDS
//    (block owns tokens [n0,n0+128)), one atomicAdd reserves a contiguous
//    run, block copies out -> list clustered by 128-token windows -> rescore
//    waves' z gathers hit ~8 cachelines/load and stay L1-hot. blist overlays
//    the dead e-staging LDS after the main loop; zero extra LDS.
//  - k_rowres: reverted to the round-11/12 proven body (thread-per-candidate,
//    lockstep 64-code partition, VGPR ~44). Bit-identical chains.
// k_prep / k_mfma main loop (incl. staging swizzle) / k_colres / k_tokens /
// k_tail byte-identical to round 16. absmax must stay 1.525879e-05.

#define MARGIN 2e-4f
#define CERT   2e-4f

// ---- ws layout (bytes) ----
#define WS_ROW   0         // u64 wsrow[65536]
#define WS_COL   524288    // u64 wscol[1024]
#define WS_CNT   532480    // u32 counts[1024]
#define WS_LOSS  536576    // double loss_acc
#define WS_EN2   536592    // float en2[1024]
#define WS_LCNT  540688    // u32 lcnt
#define WS_ZN2   541696    // float zn2[65536]            (256KB)
#define WS_EBH   803840    // u16 ebf_hi[1024*64]         (128KB)
#define WS_EBL   934912    // u16 ebf_lo[1024*64]         (128KB)
#define WS_LIST  1065984   // u32 list[65536]             (256KB)
#define WS_CBM   1328128   // f32 colbm[1024][512]        (2MB)
#define WS_BYTES 3425280
#define WS_ZERO  540720    // memset range: row/col/cnt/loss/lcnt

typedef __attribute__((ext_vector_type(8))) short short8v;
typedef __attribute__((ext_vector_type(4))) float f32x4;

__device__ __forceinline__ unsigned int f32_ord(float x) {
    unsigned int b = __float_as_uint(x);
    return (b & 0x80000000u) ? ~b : (b | 0x80000000u);
}
__device__ __forceinline__ float ord_f32(unsigned int u) {  // exact inverse
    unsigned int b = (u & 0x80000000u) ? (u & 0x7FFFFFFFu) : ~u;
    return __uint_as_float(b);
}

__device__ __forceinline__ unsigned short f2bf(float f) {  // RNE fp32->bf16
    unsigned int u = __float_as_uint(f);
    return (unsigned short)((u + 0x7FFFu + ((u >> 16) & 1u)) >> 16);
}
__device__ __forceinline__ float bf2f(unsigned short h) {
    return __uint_as_float((unsigned int)h << 16);
}

// numpy pairwise sum of squares over 64 values (verbatim from passing code).
template <typename F>
__device__ __forceinline__ float np_pairwise64_sq(F get) {
    float r[8];
#pragma unroll
    for (int j = 0; j < 8; ++j) {
        float v = get(j);
        r[j] = __fmul_rn(v, v);
    }
#pragma unroll
    for (int i = 8; i < 64; i += 8) {
#pragma unroll
        for (int j = 0; j < 8; ++j) {
            float v = get(i + j);
            r[j] = __fadd_rn(r[j], __fmul_rn(v, v));
        }
    }
    return __fadd_rn(__fadd_rn(__fadd_rn(r[0], r[1]), __fadd_rn(r[2], r[3])),
                     __fadd_rn(__fadd_rn(r[4], r[5]), __fadd_rn(r[6], r[7])));
}

// ---- K0: e-only prep: en2 + codebook bf16 hi/lo splits (4 blocks) ----
__global__ __launch_bounds__(256) void k_prep(
    const float* __restrict__ emb, float* __restrict__ en2,
    unsigned int* __restrict__ ebh32, unsigned int* __restrict__ ebl32) {
    const int t = threadIdx.x;
    const int k = blockIdx.x * 256 + t;
    const float* a = emb + (size_t)k * 64;
    float ar[64];
#pragma unroll
    for (int i = 0; i < 64; ++i) ar[i] = a[i];
    en2[k] = np_pairwise64_sq([&](int i) { return ar[i]; });
#pragma unroll
    for (int wd = 0; wd < 32; ++wd) {
        float e0 = ar[2 * wd], e1 = ar[2 * wd + 1];
        unsigned short h0 = f2bf(e0), h1 = f2bf(e1);
        ebh32[k * 32 + wd] = (unsigned int)h0 | ((unsigned int)h1 << 16);
        unsigned short l0 = f2bf(__fsub_rn(e0, bf2f(h0)));
        unsigned short l1 = f2bf(__fsub_rn(e1, bf2f(h1)));
        ebl32[k * 32 + wd] = (unsigned int)l0 | ((unsigned int)l1 << 16);
    }
}

// ---- K1: fused z-prep + s~ via bf16 MFMA + top-2 certification ----
// Main loop byte-identical to round 16. New: block-local list compaction.
__global__ __launch_bounds__(512, 2) void k_mfma(
    const float* __restrict__ z,
    const unsigned short* __restrict__ ebh, const unsigned short* __restrict__ ebl,
    float* __restrict__ zn2, const float* __restrict__ en2,
    float* __restrict__ cbm, unsigned long long* __restrict__ wsrow,
    unsigned int* __restrict__ lcnt, unsigned int* __restrict__ list) {
    const int t = threadIdx.x, l = t & 63, w = t >> 6;
    const int n0 = blockIdx.x * 128;
    const int tw = n0 + w * 16;
    const int lm = l & 15, kg = l >> 4;
    const int b   = n0 >> 12;
    const int hw0 = n0 & 4095;

    __shared__ __align__(16) unsigned char smem[45056];
    unsigned int* eh   = (unsigned int*)(smem);            // [2][64*36]
    unsigned int* el   = (unsigned int*)(smem + 18432);    // [2][64*36]
    float*        en2l = (float*)(smem + 36864);           // [1024]
    unsigned int* cmU  = (unsigned int*)(smem + 40960);    // [1024]
    float*        zl   = (float*)(smem);                   // [64][129] prologue
    float*        zntmp= (float*)(smem + 36864);           // [128]     prologue
    // epilogue carve (overlays dead e-staging region):
    int*          bcnt  = (int*)(smem);                    // [1]
    unsigned int* bbase = (unsigned int*)(smem + 4);       // [1]
    unsigned int* blist = (unsigned int*)(smem + 8);       // [128]

    // --- prologue phase 1: global z -> LDS transpose (coalesced) ---
    const float* zsrc = z + (size_t)b * 262144 + hw0;
#pragma unroll
    for (int it = 0; it < 16; ++it) {
        int idx = it * 512 + t;
        int c = idx >> 7, tok = idx & 127;
        zl[c * 129 + tok] = zsrc[(size_t)c * 4096 + tok];
    }
    __syncthreads();

    // --- prologue phase 2: zn2 (verbatim chain) + fragment assembly ---
    if (t < 128) {
        float v = np_pairwise64_sq([&](int i) { return zl[i * 129 + t]; });
        zn2[n0 + t] = v;
        zntmp[t] = v;
    }
    const int tokA = w * 16 + lm;   // block-local token of this thread's A-frag
    short8v ah0, ah1, al0, al1;
#pragma unroll
    for (int j = 0; j < 8; ++j) {
        float z0 = zl[(kg * 8 + j) * 129 + tokA];
        float z1 = zl[(32 + kg * 8 + j) * 129 + tokA];
        unsigned short h0 = f2bf(z0);
        unsigned short h1 = f2bf(z1);
        ah0[j] = (short)h0;
        ah1[j] = (short)h1;
        al0[j] = (short)f2bf(__fsub_rn(z0, bf2f(h0)));
        al1[j] = (short)f2bf(__fsub_rn(z1, bf2f(h1)));
    }
    __syncthreads();

    // --- prologue phase 3: read zn2 for this thread's C/D rows ---
    float nzn2[4];
#pragma unroll
    for (int j = 0; j < 4; ++j) nzn2[j] = -zntmp[w * 16 + kg * 4 + j];
    __syncthreads();

    // --- prologue phase 4: init en2l/cmU, stage e group 0 ---
    // Staging swizzle: word=(t&7)^(scode&7) -> conflict-free ds_write_b128;
    // global source rotates identically; LDS layout unchanged (reads fine).
    for (int i = t; i < 1024; i += 512) { en2l[i] = en2[i]; cmU[i] = 0u; }
    const uint4* EH4 = reinterpret_cast<const uint4*>(ebh);
    const uint4* EL4 = reinterpret_cast<const uint4*>(ebl);
    const int scode = t >> 3;
    const int sword = (t & 7) ^ (scode & 7);
    const int swd   = sword * 4;
    const int sidx  = scode * 8 + sword;
    {
        uint4 hv = EH4[sidx], lv = EL4[sidx];
        *reinterpret_cast<uint4*>(&eh[0 * 2304 + scode * 36 + swd]) = hv;
        *reinterpret_cast<uint4*>(&el[0 * 2304 + scode * 36 + swd]) = lv;
    }

    float v1[4] = {-3.4e38f, -3.4e38f, -3.4e38f, -3.4e38f};
    float v2[4] = {-3.4e38f, -3.4e38f, -3.4e38f, -3.4e38f};
    int   c1[4] = {0, 0, 0, 0};

    __syncthreads();

    for (int g = 0; g < 16; ++g) {
        const int buf = g & 1;
        const bool pf = (g < 15);
        uint4 hv, lv;
        if (pf) {   // issue next group's loads early; write AFTER compute
            hv = EH4[(g + 1) * 512 + sidx];
            lv = EL4[(g + 1) * 512 + sidx];
        }

#pragma unroll
        for (int sc = 0; sc < 4; ++sc) {
            const int cl = sc * 16 + lm;
            const short8v bh0 = *reinterpret_cast<const short8v*>(&eh[buf * 2304 + cl * 36 + kg * 4]);
            const short8v bh1 = *reinterpret_cast<const short8v*>(&eh[buf * 2304 + cl * 36 + 16 + kg * 4]);
            const short8v bl0 = *reinterpret_cast<const short8v*>(&el[buf * 2304 + cl * 36 + kg * 4]);
            const short8v bl1 = *reinterpret_cast<const short8v*>(&el[buf * 2304 + cl * 36 + 16 + kg * 4]);

            f32x4 a1 = {0.f, 0.f, 0.f, 0.f};
            f32x4 a2 = {0.f, 0.f, 0.f, 0.f};
            __builtin_amdgcn_s_setprio(1);
            a1 = __builtin_amdgcn_mfma_f32_16x16x32_bf16(ah0, bh0, a1, 0, 0, 0);
            a1 = __builtin_amdgcn_mfma_f32_16x16x32_bf16(ah1, bh1, a1, 0, 0, 0);
            a2 = __builtin_amdgcn_mfma_f32_16x16x32_bf16(ah0, bl0, a2, 0, 0, 0);
            a2 = __builtin_amdgcn_mfma_f32_16x16x32_bf16(ah1, bl1, a2, 0, 0, 0);
            a2 = __builtin_amdgcn_mfma_f32_16x16x32_bf16(al0, bh0, a2, 0, 0, 0);
            a2 = __builtin_amdgcn_mfma_f32_16x16x32_bf16(al1, bh1, a2, 0, 0, 0);
            __builtin_amdgcn_s_setprio(0);

            const int code = g * 64 + cl;
            const float en2v = en2l[code];
            float cm = -3.4e38f;
#pragma unroll
            for (int j = 0; j < 4; ++j) {
                float acc  = __fadd_rn(a1[j], a2[j]);
                float base = __fsub_rn(nzn2[j], en2v);
                float s    = fmaf(2.0f, acc, base);
                // top-2, min/max form (identical values to the branchy version)
                bool gt = s > v1[j];
                v2[j] = fmaxf(fminf(s, v1[j]), v2[j]);
                v1[j] = fmaxf(v1[j], s);
                c1[j] = gt ? code : c1[j];
                cm = fmaxf(cm, s);
            }
            cm = fmaxf(cm, __shfl_xor(cm, 16, 64));
            cm = fmaxf(cm, __shfl_xor(cm, 32, 64));
            if (l < 16) atomicMax(&cmU[code], f32_ord(cm));
        }

        if (pf) {
            *reinterpret_cast<uint4*>(&eh[(buf ^ 1) * 2304 + scode * 36 + swd]) = hv;
            *reinterpret_cast<uint4*>(&el[(buf ^ 1) * 2304 + scode * 36 + swd]) = lv;
        }
        __syncthreads();
    }

    // ---- row finalize: merge top-2, certify; uncertified -> LDS blist ----
    if (t == 0) *bcnt = 0;
    __syncthreads();
#pragma unroll
    for (int j = 0; j < 4; ++j) {
        unsigned long long key =
            ((unsigned long long)f32_ord(v1[j]) << 32) |
            (unsigned long long)(unsigned int)(~(unsigned int)c1[j]);
        float w2 = v2[j];
#pragma unroll
        for (int m = 1; m < 16; m <<= 1) {
            unsigned long long ok = __shfl_xor(key, m, 64);
            float ov2 = __shfl_xor(w2, m, 64);
            unsigned long long lk = (key < ok) ? key : ok;   // losing top1
            float lv2 = ord_f32((unsigned int)(lk >> 32));
            w2 = fmaxf(fmaxf(w2, ov2), lv2);
            key = (key > ok) ? key : ok;                      // ties: smaller c
        }
        if (lm == 0) {
            const int tn = tw + kg * 4 + j;
            float v1m = ord_f32((unsigned int)(key >> 32));
            if (__fsub_rn(v1m, w2) > CERT) {
                wsrow[tn] = key;      // certified: provably exact argmax index
            } else {
                int p = atomicAdd(bcnt, 1);
                blist[p] = (unsigned int)tn;
            }
        }
    }
    __syncthreads();
    if (t == 0 && *bcnt > 0) *bbase = atomicAdd(lcnt, (unsigned int)*bcnt);
    __syncthreads();
    {
        const int cb2 = *bcnt;
        for (int i = t; i < cb2; i += 512) list[*bbase + i] = blist[i];
    }

    for (int code = t; code < 1024; code += 512)
        cbm[(size_t)code * 512 + blockIdx.x] = ord_f32(cmU[code]);
}

// ---- K2a: exact column rescore (own launch: low VGPR, high occupancy) ----
__global__ __launch_bounds__(256) void k_colres(
    const float* __restrict__ z, const float* __restrict__ emb,
    const float* __restrict__ zn2, const float* __restrict__ en2,
    const float* __restrict__ cbm, unsigned long long* __restrict__ wscol) {
    const int k = blockIdx.x, t = threadIdx.x;
    __shared__ float red[256];
    __shared__ int   hlist[512];
    __shared__ int   hcnt;
    float a  = cbm[(size_t)k * 512 + t];
    float b2 = cbm[(size_t)k * 512 + 256 + t];
    red[t] = fmaxf(a, b2);
    if (t == 0) hcnt = 0;
    __syncthreads();
    for (int st = 128; st; st >>= 1) {
        if (t < st) red[t] = fmaxf(red[t], red[t + st]);
        __syncthreads();
    }
    const float thr = red[0] - MARGIN;
    if (a >= thr)  { int p = atomicAdd(&hcnt, 1); hlist[p] = t; }
    if (b2 >= thr) { int p = atomicAdd(&hcnt, 1); hlist[p] = t + 256; }
    __syncthreads();
    const int hc = hcnt;
    const float en2k = en2[k];
    const float4* ek = reinterpret_cast<const float4*>(emb + (size_t)k * 64);

    for (int h = 0; h < hc; ++h) {
        const int g = hlist[h];
        if (t < 128) {
            const int n = g * 128 + t;
            const int b = n >> 12, hw = n & 4095;
            const float* zp = z + (size_t)b * 262144 + hw;
            float c0 = 0.f, c1 = 0.f, c2 = 0.f, c3 = 0.f;
#pragma unroll
            for (int j = 0; j < 16; ++j) {
                float4 e = ek[j];
                c0 = fmaf(e.x, zp[(size_t)(4 * j + 0) * 4096], c0);
                c1 = fmaf(e.y, zp[(size_t)(4 * j + 1) * 4096], c1);
                c2 = fmaf(e.z, zp[(size_t)(4 * j + 2) * 4096], c2);
                c3 = fmaf(e.w, zp[(size_t)(4 * j + 3) * 4096], c3);
            }
            float dot = (c0 + c1) + (c2 + c3);
            float d = __fadd_rn(__fsub_rn(-zn2[n], en2k), 2.0f * dot);
            unsigned long long key =
                ((unsigned long long)f32_ord(d) << 32) |
                (unsigned long long)(unsigned int)(~(unsigned int)n);
#pragma unroll
            for (int m = 1; m < 64; m <<= 1) {
                unsigned long long o = __shfl_xor(key, m, 64);
                if (o > key) key = o;    // ties: larger key = smaller n
            }
            if ((t & 63) == 0) atomicMax(&wscol[k], key);
        }
    }
}

// ---- K2b: exact row rescore — round-11/12 proven low-VGPR body ----
// grid (64,16): blockIdx.y = 64-code partition (k wave-uniform -> s_load),
// grid-stride over the (now block-clustered) list. Verbatim 4-chain fmaf.
__global__ __launch_bounds__(256) void k_rowres(
    const float* __restrict__ z, const float* __restrict__ emb,
    const float* __restrict__ zn2, const float* __restrict__ en2,
    const unsigned int* __restrict__ list, const unsigned int* __restrict__ lcnt,
    unsigned long long* __restrict__ wsrow) {
    const unsigned int cnt = *lcnt;
    const int k0 = blockIdx.y * 64;
    const float4* E4 = reinterpret_cast<const float4*>(emb);
    for (unsigned int i = blockIdx.x * 256 + threadIdx.x; i < cnt;
         i += 64 * 256) {
        const int n = (int)list[i];
        const int b = n >> 12, hw = n & 4095;
        const float* zp = z + (size_t)b * 262144 + hw;
        const float nz = -zn2[n];
        unsigned long long best = 0ull;
        for (int kk = 0; kk < 64; ++kk) {
            const int k = k0 + kk;                   // wave-uniform -> s_load
            const float4* ek = E4 + (size_t)k * 16;
            float c0 = 0.f, c1 = 0.f, c2 = 0.f, c3 = 0.f;
#pragma unroll
            for (int j = 0; j < 16; ++j) {
                float4 e = ek[j];
                c0 = fmaf(e.x, zp[(size_t)(4 * j + 0) * 4096], c0);
                c1 = fmaf(e.y, zp[(size_t)(4 * j + 1) * 4096], c1);
                c2 = fmaf(e.z, zp[(size_t)(4 * j + 2) * 4096], c2);
                c3 = fmaf(e.w, zp[(size_t)(4 * j + 3) * 4096], c3);
            }
            float dot = (c0 + c1) + (c2 + c3);
            float d = __fadd_rn(__fsub_rn(nz, en2[k]), 2.0f * dot);
            unsigned long long key =
                ((unsigned long long)f32_ord(d) << 32) |
                (unsigned long long)(unsigned int)(~(unsigned int)k);
            if (key > best) best = key;   // ties: larger key = smaller k
        }
        atomicMax(&wsrow[n], best);
    }
}

// ---- K3: per-token outputs, 4-way channel split (1024 blocks) ----
__global__ __launch_bounds__(256) void k_tokens(
    const float* __restrict__ z, const float* __restrict__ emb,
    const unsigned long long* __restrict__ wsrow,
    unsigned int* __restrict__ counts, double* __restrict__ loss_acc,
    float* __restrict__ out_zq, float* __restrict__ out_idx) {
    const int t    = threadIdx.x;
    const int lane = t & 63;
    const int q    = t >> 6;
    const int n    = blockIdx.x * 64 + lane;
    const int b    = n >> 12;
    const int hw   = n & 4095;

    unsigned long long key = wsrow[n];
    int idx = (int)(~(unsigned int)(key & 0xFFFFFFFFull));
    if (q == 0) {
        out_idx[n] = (float)idx;
        atomicAdd(&counts[idx], 1u);
    }

    const float* zp = z + (size_t)b * 262144 + hw;
    float*       op = out_zq + (size_t)b * 262144 + hw;
    const float* ep = emb + (size_t)idx * 64;

    double ls = 0.0;
#pragma unroll
    for (int c = q * 16; c < q * 16 + 16; ++c) {
        float zc   = zp[(size_t)c * 4096];
        float eq   = ep[c];
        float diff = __fsub_rn(eq, zc);              // fl(z_q - zc)
        float sq   = __fmul_rn(diff, diff);
        ls += (double)sq;
        op[(size_t)c * 4096] = __fadd_rn(zc, diff);  // zc + fl(z_q - zc)
    }

    __shared__ double sred[256];
    sred[q * 64 + lane] = ls;
    __syncthreads();
    if (t < 64) {
        sred[t] = (sred[t] + sred[64 + t]) + (sred[128 + t] + sred[192 + t]);
    }
    __syncthreads();
    for (int st = 32; st; st >>= 1) {
        if (t < st) sred[t] += sred[t + st];
        __syncthreads();
    }
    if (t == 0) atomicAdd(loss_acc, sred[0]);
}

// ---- K4: tail — new embedding + scalars (unchanged) ----
__global__ __launch_bounds__(1024) void k_tail(
    const float* __restrict__ z, const float* __restrict__ emb,
    const float* __restrict__ embed_prob,
    const unsigned long long* __restrict__ wscol,
    const unsigned int* __restrict__ counts,
    const double* __restrict__ loss_acc,
    float* __restrict__ out_newemb, float* __restrict__ out_loss,
    float* __restrict__ out_perp, float* __restrict__ out_prob) {
    const int k = blockIdx.x * 16 + (threadIdx.x >> 6);
    const int c = threadIdx.x & 63;

    float avg  = (float)counts[k] * (1.0f / 65536.0f);
    float pnew = __fadd_rn(__fmul_rn(embed_prob[k], 0.99f),
                           __fmul_rn(0.01f, avg));
    float tt = __fdiv_rn(__fmul_rn(__fmul_rn(pnew, 1024.0f), 10.0f), 0.01f);
    float dk = expf(__fsub_rn(-tt, 1e-3f));
    float omd = __fsub_rn(1.0f, dk);

    unsigned long long ck = wscol[k];
    int cn  = (int)(~(unsigned int)(ck & 0xFFFFFFFFull));
    int cb  = cn >> 12;
    int chw = cn & 4095;

    float rf = z[(size_t)cb * 262144 + (size_t)c * 4096 + chw];
    float e  = emb[(size_t)k * 64 + c];
    out_newemb[(size_t)k * 64 + c] =
        __fadd_rn(__fmul_rn(e, omd), __fmul_rn(rf, dk));

    if (blockIdx.x == 0) {
        const int q = threadIdx.x;

        float avg2  = (float)counts[q] * (1.0f / 65536.0f);
        float pnew2 = __fadd_rn(__fmul_rn(embed_prob[q], 0.99f),
                                __fmul_rn(0.01f, avg2));
        out_prob[q] = pnew2;

        float term = __fmul_rn(avg2, logf(__fadd_rn(avg2, 1e-10f)));
        __shared__ double red[1024];
        red[q] = (double)term;
        __syncthreads();
        for (int st = 512; st; st >>= 1) {
            if (q < st) red[q] += red[q + st];
            __syncthreads();
        }
        if (q == 0) {
            float s32 = (float)red[0];
            out_perp[0] = expf(-s32);
            double lm = loss_acc[0] / 4194304.0;
            float  m  = (float)lm;
            out_loss[0] = __fadd_rn(__fmul_rn(0.25f, m), m);  // BETA*m + m
        }
    }
}

extern "C" void kernel_launch(void* const* d_in, const int* in_sizes, int n_in,
                              void* d_out, int out_size, void* d_ws, size_t ws_size,
                              hipStream_t stream) {
    const float* z    = (const float*)d_in[0];   // 16*64*64*64
    const float* emb  = (const float*)d_in[1];   // 1024*64
    const float* prob = (const float*)d_in[2];   // 1024

    float* out        = (float*)d_out;
    float* out_zq     = out;                 // 4194304 floats
    float* out_loss   = out + 4194304;
    float* out_perp   = out + 4194305;
    float* out_newemb = out + 4194306;
    float* out_prob   = out + 4259842;
    float* out_idx    = out + 4260866;

    char* ws = (char*)d_ws;
    unsigned long long* wsrow = (unsigned long long*)(ws + WS_ROW);
    unsigned long long* wscol = (unsigned long long*)(ws + WS_COL);
    unsigned int*       cnts  = (unsigned int*)(ws + WS_CNT);
    double*             lacc  = (double*)(ws + WS_LOSS);
    float*              en2   = (float*)(ws + WS_EN2);
    unsigned int*       lcnt  = (unsigned int*)(ws + WS_LCNT);
    float*              zn2   = (float*)(ws + WS_ZN2);
    unsigned short*     ebh   = (unsigned short*)(ws + WS_EBH);
    unsigned short*     ebl   = (unsigned short*)(ws + WS_EBL);
    unsigned int*       list  = (unsigned int*)(ws + WS_LIST);
    float*              cbm   = (float*)(ws + WS_CBM);

    hipMemsetAsync(d_ws, 0, WS_ZERO, stream);

    hipLaunchKernelGGL(k_prep, dim3(4), dim3(256), 0, stream,
                       emb, en2, (unsigned int*)ebh, (unsigned int*)ebl);
    hipLaunchKernelGGL(k_mfma, dim3(512), dim3(512), 0, stream,
                       z, ebh, ebl, zn2, en2, cbm, wsrow, lcnt, list);
    hipLaunchKernelGGL(k_colres, dim3(1024), dim3(256), 0, stream,
                       z, emb, zn2, en2, cbm, wscol);
    hipLaunchKernelGGL(k_rowres, dim3(64, 16), dim3(256), 0, stream,
                       z, emb, zn2, en2, list, lcnt, wsrow);
    hipLaunchKernelGGL(k_tokens, dim3(1024), dim3(256), 0, stream,
                       z, emb, wsrow, cnts, lacc, out_zq, out_idx);
    hipLaunchKernelGGL(k_tail, dim3(64), dim3(1024), 0, stream,
                       z, emb, prob, wscol, cnts, lacc,
                       out_newemb, out_loss, out_perp, out_prob);
}

// Round 16
// 206.231 us; speedup vs baseline: 1.5234x; 1.0441x over previous
//
#include <hip/hip_runtime.h>

// VectorQuantiser forward, MI355X fp32.
// N=65536 tokens (16x64x64, channel dim 64 strided by 4096), K=1024 codes, D=64.
//
// Round 18. Round-17 gave 215.3us (best): compaction fixed rowres 123->60
// (and k_mfma 93->60 -- the removed 65K serialized global atomicAdds, NOT the
// staging swizzle: SQ_LDS_BANK_CONFLICT unchanged at 4.33M; that counter is
// intrinsic to the b128 staging pattern and does not correlate with dur).
// Remaining diagnosis: k_rowres Occ 10.6%/VALU 9% = thread-count starvation
// (cnt*16 partitions ~ 100K threads ~ 2 waves/CU, serial 64-code chains).
// This round:
//  - k_colres + k_rowres re-merged into ONE k_rescore launch (both bodies
//    are low-VGPR now: 50/44 -- round-13's merge failure was purely the
//    VGPR-108 register-blocked row body). Col waves fill row latency.
//  - row part: 64 partitions x 16 codes (was 16x64): 4x threads, 4x shorter
//    serial chains; z stays L1-hot in the compacted 128-token windows.
//    Per-code chains verbatim -> bit-identical keys; atomicMax merge.
// k_prep / k_mfma / k_tokens / k_tail byte-identical to round 17.
// absmax must stay 1.525879e-05.

#define MARGIN 2e-4f
#define CERT   2e-4f

// ---- ws layout (bytes) ----
#define WS_ROW   0         // u64 wsrow[65536]
#define WS_COL   524288    // u64 wscol[1024]
#define WS_CNT   532480    // u32 counts[1024]
#define WS_LOSS  536576    // double loss_acc
#define WS_EN2   536592    // float en2[1024]
#define WS_LCNT  540688    // u32 lcnt
#define WS_ZN2   541696    // float zn2[65536]            (256KB)
#define WS_EBH   803840    // u16 ebf_hi[1024*64]         (128KB)
#define WS_EBL   934912    // u16 ebf_lo[1024*64]         (128KB)
#define WS_LIST  1065984   // u32 list[65536]             (256KB)
#define WS_CBM   1328128   // f32 colbm[1024][512]        (2MB)
#define WS_BYTES 3425280
#define WS_ZERO  540720    // memset range: row/col/cnt/loss/lcnt

typedef __attribute__((ext_vector_type(8))) short short8v;
typedef __attribute__((ext_vector_type(4))) float f32x4;

__device__ __forceinline__ unsigned int f32_ord(float x) {
    unsigned int b = __float_as_uint(x);
    return (b & 0x80000000u) ? ~b : (b | 0x80000000u);
}
__device__ __forceinline__ float ord_f32(unsigned int u) {  // exact inverse
    unsigned int b = (u & 0x80000000u) ? (u & 0x7FFFFFFFu) : ~u;
    return __uint_as_float(b);
}

__device__ __forceinline__ unsigned short f2bf(float f) {  // RNE fp32->bf16
    unsigned int u = __float_as_uint(f);
    return (unsigned short)((u + 0x7FFFu + ((u >> 16) & 1u)) >> 16);
}
__device__ __forceinline__ float bf2f(unsigned short h) {
    return __uint_as_float((unsigned int)h << 16);
}

// numpy pairwise sum of squares over 64 values (verbatim from passing code).
template <typename F>
__device__ __forceinline__ float np_pairwise64_sq(F get) {
    float r[8];
#pragma unroll
    for (int j = 0; j < 8; ++j) {
        float v = get(j);
        r[j] = __fmul_rn(v, v);
    }
#pragma unroll
    for (int i = 8; i < 64; i += 8) {
#pragma unroll
        for (int j = 0; j < 8; ++j) {
            float v = get(i + j);
            r[j] = __fadd_rn(r[j], __fmul_rn(v, v));
        }
    }
    return __fadd_rn(__fadd_rn(__fadd_rn(r[0], r[1]), __fadd_rn(r[2], r[3])),
                     __fadd_rn(__fadd_rn(r[4], r[5]), __fadd_rn(r[6], r[7])));
}

// ---- K0: e-only prep: en2 + codebook bf16 hi/lo splits (4 blocks) ----
__global__ __launch_bounds__(256) void k_prep(
    const float* __restrict__ emb, float* __restrict__ en2,
    unsigned int* __restrict__ ebh32, unsigned int* __restrict__ ebl32) {
    const int t = threadIdx.x;
    const int k = blockIdx.x * 256 + t;
    const float* a = emb + (size_t)k * 64;
    float ar[64];
#pragma unroll
    for (int i = 0; i < 64; ++i) ar[i] = a[i];
    en2[k] = np_pairwise64_sq([&](int i) { return ar[i]; });
#pragma unroll
    for (int wd = 0; wd < 32; ++wd) {
        float e0 = ar[2 * wd], e1 = ar[2 * wd + 1];
        unsigned short h0 = f2bf(e0), h1 = f2bf(e1);
        ebh32[k * 32 + wd] = (unsigned int)h0 | ((unsigned int)h1 << 16);
        unsigned short l0 = f2bf(__fsub_rn(e0, bf2f(h0)));
        unsigned short l1 = f2bf(__fsub_rn(e1, bf2f(h1)));
        ebl32[k * 32 + wd] = (unsigned int)l0 | ((unsigned int)l1 << 16);
    }
}

// ---- K1: fused z-prep + s~ via bf16 MFMA + top-2 certification ----
// (byte-identical to round 17)
__global__ __launch_bounds__(512, 2) void k_mfma(
    const float* __restrict__ z,
    const unsigned short* __restrict__ ebh, const unsigned short* __restrict__ ebl,
    float* __restrict__ zn2, const float* __restrict__ en2,
    float* __restrict__ cbm, unsigned long long* __restrict__ wsrow,
    unsigned int* __restrict__ lcnt, unsigned int* __restrict__ list) {
    const int t = threadIdx.x, l = t & 63, w = t >> 6;
    const int n0 = blockIdx.x * 128;
    const int tw = n0 + w * 16;
    const int lm = l & 15, kg = l >> 4;
    const int b   = n0 >> 12;
    const int hw0 = n0 & 4095;

    __shared__ __align__(16) unsigned char smem[45056];
    unsigned int* eh   = (unsigned int*)(smem);            // [2][64*36]
    unsigned int* el   = (unsigned int*)(smem + 18432);    // [2][64*36]
    float*        en2l = (float*)(smem + 36864);           // [1024]
    unsigned int* cmU  = (unsigned int*)(smem + 40960);    // [1024]
    float*        zl   = (float*)(smem);                   // [64][129] prologue
    float*        zntmp= (float*)(smem + 36864);           // [128]     prologue
    // epilogue carve (overlays dead e-staging region):
    int*          bcnt  = (int*)(smem);                    // [1]
    unsigned int* bbase = (unsigned int*)(smem + 4);       // [1]
    unsigned int* blist = (unsigned int*)(smem + 8);       // [128]

    // --- prologue phase 1: global z -> LDS transpose (coalesced) ---
    const float* zsrc = z + (size_t)b * 262144 + hw0;
#pragma unroll
    for (int it = 0; it < 16; ++it) {
        int idx = it * 512 + t;
        int c = idx >> 7, tok = idx & 127;
        zl[c * 129 + tok] = zsrc[(size_t)c * 4096 + tok];
    }
    __syncthreads();

    // --- prologue phase 2: zn2 (verbatim chain) + fragment assembly ---
    if (t < 128) {
        float v = np_pairwise64_sq([&](int i) { return zl[i * 129 + t]; });
        zn2[n0 + t] = v;
        zntmp[t] = v;
    }
    const int tokA = w * 16 + lm;   // block-local token of this thread's A-frag
    short8v ah0, ah1, al0, al1;
#pragma unroll
    for (int j = 0; j < 8; ++j) {
        float z0 = zl[(kg * 8 + j) * 129 + tokA];
        float z1 = zl[(32 + kg * 8 + j) * 129 + tokA];
        unsigned short h0 = f2bf(z0);
        unsigned short h1 = f2bf(z1);
        ah0[j] = (short)h0;
        ah1[j] = (short)h1;
        al0[j] = (short)f2bf(__fsub_rn(z0, bf2f(h0)));
        al1[j] = (short)f2bf(__fsub_rn(z1, bf2f(h1)));
    }
    __syncthreads();

    // --- prologue phase 3: read zn2 for this thread's C/D rows ---
    float nzn2[4];
#pragma unroll
    for (int j = 0; j < 4; ++j) nzn2[j] = -zntmp[w * 16 + kg * 4 + j];
    __syncthreads();

    // --- prologue phase 4: init en2l/cmU, stage e group 0 ---
    for (int i = t; i < 1024; i += 512) { en2l[i] = en2[i]; cmU[i] = 0u; }
    const uint4* EH4 = reinterpret_cast<const uint4*>(ebh);
    const uint4* EL4 = reinterpret_cast<const uint4*>(ebl);
    const int scode = t >> 3;
    const int sword = (t & 7) ^ (scode & 7);
    const int swd   = sword * 4;
    const int sidx  = scode * 8 + sword;
    {
        uint4 hv = EH4[sidx], lv = EL4[sidx];
        *reinterpret_cast<uint4*>(&eh[0 * 2304 + scode * 36 + swd]) = hv;
        *reinterpret_cast<uint4*>(&el[0 * 2304 + scode * 36 + swd]) = lv;
    }

    float v1[4] = {-3.4e38f, -3.4e38f, -3.4e38f, -3.4e38f};
    float v2[4] = {-3.4e38f, -3.4e38f, -3.4e38f, -3.4e38f};
    int   c1[4] = {0, 0, 0, 0};

    __syncthreads();

    for (int g = 0; g < 16; ++g) {
        const int buf = g & 1;
        const bool pf = (g < 15);
        uint4 hv, lv;
        if (pf) {   // issue next group's loads early; write AFTER compute
            hv = EH4[(g + 1) * 512 + sidx];
            lv = EL4[(g + 1) * 512 + sidx];
        }

#pragma unroll
        for (int sc = 0; sc < 4; ++sc) {
            const int cl = sc * 16 + lm;
            const short8v bh0 = *reinterpret_cast<const short8v*>(&eh[buf * 2304 + cl * 36 + kg * 4]);
            const short8v bh1 = *reinterpret_cast<const short8v*>(&eh[buf * 2304 + cl * 36 + 16 + kg * 4]);
            const short8v bl0 = *reinterpret_cast<const short8v*>(&el[buf * 2304 + cl * 36 + kg * 4]);
            const short8v bl1 = *reinterpret_cast<const short8v*>(&el[buf * 2304 + cl * 36 + 16 + kg * 4]);

            f32x4 a1 = {0.f, 0.f, 0.f, 0.f};
            f32x4 a2 = {0.f, 0.f, 0.f, 0.f};
            __builtin_amdgcn_s_setprio(1);
            a1 = __builtin_amdgcn_mfma_f32_16x16x32_bf16(ah0, bh0, a1, 0, 0, 0);
            a1 = __builtin_amdgcn_mfma_f32_16x16x32_bf16(ah1, bh1, a1, 0, 0, 0);
            a2 = __builtin_amdgcn_mfma_f32_16x16x32_bf16(ah0, bl0, a2, 0, 0, 0);
            a2 = __builtin_amdgcn_mfma_f32_16x16x32_bf16(ah1, bl1, a2, 0, 0, 0);
            a2 = __builtin_amdgcn_mfma_f32_16x16x32_bf16(al0, bh0, a2, 0, 0, 0);
            a2 = __builtin_amdgcn_mfma_f32_16x16x32_bf16(al1, bh1, a2, 0, 0, 0);
            __builtin_amdgcn_s_setprio(0);

            const int code = g * 64 + cl;
            const float en2v = en2l[code];
            float cm = -3.4e38f;
#pragma unroll
            for (int j = 0; j < 4; ++j) {
                float acc  = __fadd_rn(a1[j], a2[j]);
                float base = __fsub_rn(nzn2[j], en2v);
                float s    = fmaf(2.0f, acc, base);
                // top-2, min/max form (identical values to the branchy version)
                bool gt = s > v1[j];
                v2[j] = fmaxf(fminf(s, v1[j]), v2[j]);
                v1[j] = fmaxf(v1[j], s);
                c1[j] = gt ? code : c1[j];
                cm = fmaxf(cm, s);
            }
            cm = fmaxf(cm, __shfl_xor(cm, 16, 64));
            cm = fmaxf(cm, __shfl_xor(cm, 32, 64));
            if (l < 16) atomicMax(&cmU[code], f32_ord(cm));
        }

        if (pf) {
            *reinterpret_cast<uint4*>(&eh[(buf ^ 1) * 2304 + scode * 36 + swd]) = hv;
            *reinterpret_cast<uint4*>(&el[(buf ^ 1) * 2304 + scode * 36 + swd]) = lv;
        }
        __syncthreads();
    }

    // ---- row finalize: merge top-2, certify; uncertified -> LDS blist ----
    if (t == 0) *bcnt = 0;
    __syncthreads();
#pragma unroll
    for (int j = 0; j < 4; ++j) {
        unsigned long long key =
            ((unsigned long long)f32_ord(v1[j]) << 32) |
            (unsigned long long)(unsigned int)(~(unsigned int)c1[j]);
        float w2 = v2[j];
#pragma unroll
        for (int m = 1; m < 16; m <<= 1) {
            unsigned long long ok = __shfl_xor(key, m, 64);
            float ov2 = __shfl_xor(w2, m, 64);
            unsigned long long lk = (key < ok) ? key : ok;   // losing top1
            float lv2 = ord_f32((unsigned int)(lk >> 32));
            w2 = fmaxf(fmaxf(w2, ov2), lv2);
            key = (key > ok) ? key : ok;                      // ties: smaller c
        }
        if (lm == 0) {
            const int tn = tw + kg * 4 + j;
            float v1m = ord_f32((unsigned int)(key >> 32));
            if (__fsub_rn(v1m, w2) > CERT) {
                wsrow[tn] = key;      // certified: provably exact argmax index
            } else {
                int p = atomicAdd(bcnt, 1);
                blist[p] = (unsigned int)tn;
            }
        }
    }
    __syncthreads();
    if (t == 0 && *bcnt > 0) *bbase = atomicAdd(lcnt, (unsigned int)*bcnt);
    __syncthreads();
    {
        const int cb2 = *bcnt;
        for (int i = t; i < cb2; i += 512) list[*bbase + i] = blist[i];
    }

    for (int code = t; code < 1024; code += 512)
        cbm[(size_t)code * 512 + blockIdx.x] = ord_f32(cmU[code]);
}

// ---- K2: merged exact rescore. Col: blocks 0..1023 (verbatim body).
// Row: blocks 1024..5119 = 64 x-slots x 64 partitions of 16 codes.
// Both low-VGPR; col waves fill the row part's latency bubbles.
__global__ __launch_bounds__(256) void k_rescore(
    const float* __restrict__ z, const float* __restrict__ emb,
    const float* __restrict__ zn2, const float* __restrict__ en2,
    const float* __restrict__ cbm,
    const unsigned int* __restrict__ list, const unsigned int* __restrict__ lcnt,
    unsigned long long* __restrict__ wscol,
    unsigned long long* __restrict__ wsrow) {
    const int t = threadIdx.x;
    if (blockIdx.x < 1024) {
        // -- column rescore: block per code --
        const int k = blockIdx.x;
        __shared__ float red[256];
        __shared__ int   hlist[512];
        __shared__ int   hcnt;
        float a  = cbm[(size_t)k * 512 + t];
        float b2 = cbm[(size_t)k * 512 + 256 + t];
        red[t] = fmaxf(a, b2);
        if (t == 0) hcnt = 0;
        __syncthreads();
        for (int st = 128; st; st >>= 1) {
            if (t < st) red[t] = fmaxf(red[t], red[t + st]);
            __syncthreads();
        }
        const float thr = red[0] - MARGIN;
        if (a >= thr)  { int p = atomicAdd(&hcnt, 1); hlist[p] = t; }
        if (b2 >= thr) { int p = atomicAdd(&hcnt, 1); hlist[p] = t + 256; }
        __syncthreads();
        const int hc = hcnt;
        const float en2k = en2[k];
        const float4* ek = reinterpret_cast<const float4*>(emb + (size_t)k * 64);

        for (int h = 0; h < hc; ++h) {
            const int g = hlist[h];
            if (t < 128) {
                const int n = g * 128 + t;
                const int b = n >> 12, hw = n & 4095;
                const float* zp = z + (size_t)b * 262144 + hw;
                float c0 = 0.f, c1 = 0.f, c2 = 0.f, c3 = 0.f;
#pragma unroll
                for (int j = 0; j < 16; ++j) {
                    float4 e = ek[j];
                    c0 = fmaf(e.x, zp[(size_t)(4 * j + 0) * 4096], c0);
                    c1 = fmaf(e.y, zp[(size_t)(4 * j + 1) * 4096], c1);
                    c2 = fmaf(e.z, zp[(size_t)(4 * j + 2) * 4096], c2);
                    c3 = fmaf(e.w, zp[(size_t)(4 * j + 3) * 4096], c3);
                }
                float dot = (c0 + c1) + (c2 + c3);
                float d = __fadd_rn(__fsub_rn(-zn2[n], en2k), 2.0f * dot);
                unsigned long long key =
                    ((unsigned long long)f32_ord(d) << 32) |
                    (unsigned long long)(unsigned int)(~(unsigned int)n);
#pragma unroll
                for (int m = 1; m < 64; m <<= 1) {
                    unsigned long long o = __shfl_xor(key, m, 64);
                    if (o > key) key = o;    // ties: larger key = smaller n
                }
                if ((t & 63) == 0) atomicMax(&wscol[k], key);
            }
        }
    } else {
        // -- row rescore: 64 partitions x 16 codes, thread-per-candidate --
        const int bid2 = blockIdx.x - 1024;        // [0, 4096)
        const int k0 = (bid2 & 63) * 16;           // 16-code partition
        const int xs = bid2 >> 6;                  // x-slot [0, 64)
        const unsigned int cnt = *lcnt;
        const float4* E4 = reinterpret_cast<const float4*>(emb);
        for (unsigned int i = (unsigned int)xs * 256 + t; i < cnt;
             i += 64 * 256) {
            const int n = (int)list[i];
            const int b = n >> 12, hw = n & 4095;
            const float* zp = z + (size_t)b * 262144 + hw;
            const float nz = -zn2[n];
            unsigned long long best = 0ull;
            for (int kk = 0; kk < 16; ++kk) {
                const int k = k0 + kk;               // wave-uniform -> s_load
                const float4* ek = E4 + (size_t)k * 16;
                float c0 = 0.f, c1 = 0.f, c2 = 0.f, c3 = 0.f;
#pragma unroll
                for (int j = 0; j < 16; ++j) {
                    float4 e = ek[j];
                    c0 = fmaf(e.x, zp[(size_t)(4 * j + 0) * 4096], c0);
                    c1 = fmaf(e.y, zp[(size_t)(4 * j + 1) * 4096], c1);
                    c2 = fmaf(e.z, zp[(size_t)(4 * j + 2) * 4096], c2);
                    c3 = fmaf(e.w, zp[(size_t)(4 * j + 3) * 4096], c3);
                }
                float dot = (c0 + c1) + (c2 + c3);
                float d = __fadd_rn(__fsub_rn(nz, en2[k]), 2.0f * dot);
                unsigned long long key =
                    ((unsigned long long)f32_ord(d) << 32) |
                    (unsigned long long)(unsigned int)(~(unsigned int)k);
                if (key > best) best = key;   // ties: larger key = smaller k
            }
            atomicMax(&wsrow[n], best);
        }
    }
}

// ---- K3: per-token outputs, 4-way channel split (1024 blocks) ----
__global__ __launch_bounds__(256) void k_tokens(
    const float* __restrict__ z, const float* __restrict__ emb,
    const unsigned long long* __restrict__ wsrow,
    unsigned int* __restrict__ counts, double* __restrict__ loss_acc,
    float* __restrict__ out_zq, float* __restrict__ out_idx) {
    const int t    = threadIdx.x;
    const int lane = t & 63;
    const int q    = t >> 6;
    const int n    = blockIdx.x * 64 + lane;
    const int b    = n >> 12;
    const int hw   = n & 4095;

    unsigned long long key = wsrow[n];
    int idx = (int)(~(unsigned int)(key & 0xFFFFFFFFull));
    if (q == 0) {
        out_idx[n] = (float)idx;
        atomicAdd(&counts[idx], 1u);
    }

    const float* zp = z + (size_t)b * 262144 + hw;
    float*       op = out_zq + (size_t)b * 262144 + hw;
    const float* ep = emb + (size_t)idx * 64;

    double ls = 0.0;
#pragma unroll
    for (int c = q * 16; c < q * 16 + 16; ++c) {
        float zc   = zp[(size_t)c * 4096];
        float eq   = ep[c];
        float diff = __fsub_rn(eq, zc);              // fl(z_q - zc)
        float sq   = __fmul_rn(diff, diff);
        ls += (double)sq;
        op[(size_t)c * 4096] = __fadd_rn(zc, diff);  // zc + fl(z_q - zc)
    }

    __shared__ double sred[256];
    sred[q * 64 + lane] = ls;
    __syncthreads();
    if (t < 64) {
        sred[t] = (sred[t] + sred[64 + t]) + (sred[128 + t] + sred[192 + t]);
    }
    __syncthreads();
    for (int st = 32; st; st >>= 1) {
        if (t < st) sred[t] += sred[t + st];
        __syncthreads();
    }
    if (t == 0) atomicAdd(loss_acc, sred[0]);
}

// ---- K4: tail — new embedding + scalars (unchanged) ----
__global__ __launch_bounds__(1024) void k_tail(
    const float* __restrict__ z, const float* __restrict__ emb,
    const float* __restrict__ embed_prob,
    const unsigned long long* __restrict__ wscol,
    const unsigned int* __restrict__ counts,
    const double* __restrict__ loss_acc,
    float* __restrict__ out_newemb, float* __restrict__ out_loss,
    float* __restrict__ out_perp, float* __restrict__ out_prob) {
    const int k = blockIdx.x * 16 + (threadIdx.x >> 6);
    const int c = threadIdx.x & 63;

    float avg  = (float)counts[k] * (1.0f / 65536.0f);
    float pnew = __fadd_rn(__fmul_rn(embed_prob[k], 0.99f),
                           __fmul_rn(0.01f, avg));
    float tt = __fdiv_rn(__fmul_rn(__fmul_rn(pnew, 1024.0f), 10.0f), 0.01f);
    float dk = expf(__fsub_rn(-tt, 1e-3f));
    float omd = __fsub_rn(1.0f, dk);

    unsigned long long ck = wscol[k];
    int cn  = (int)(~(unsigned int)(ck & 0xFFFFFFFFull));
    int cb  = cn >> 12;
    int chw = cn & 4095;

    float rf = z[(size_t)cb * 262144 + (size_t)c * 4096 + chw];
    float e  = emb[(size_t)k * 64 + c];
    out_newemb[(size_t)k * 64 + c] =
        __fadd_rn(__fmul_rn(e, omd), __fmul_rn(rf, dk));

    if (blockIdx.x == 0) {
        const int q = threadIdx.x;

        float avg2  = (float)counts[q] * (1.0f / 65536.0f);
        float pnew2 = __fadd_rn(__fmul_rn(embed_prob[q], 0.99f),
                                __fmul_rn(0.01f, avg2));
        out_prob[q] = pnew2;

        float term = __fmul_rn(avg2, logf(__fadd_rn(avg2, 1e-10f)));
        __shared__ double red[1024];
        red[q] = (double)term;
        __syncthreads();
        for (int st = 512; st; st >>= 1) {
            if (q < st) red[q] += red[q + st];
            __syncthreads();
        }
        if (q == 0) {
            float s32 = (float)red[0];
            out_perp[0] = expf(-s32);
            double lm = loss_acc[0] / 4194304.0;
            float  m  = (float)lm;
            out_loss[0] = __fadd_rn(__fmul_rn(0.25f, m), m);  // BETA*m + m
        }
    }
}

extern "C" void kernel_launch(void* const* d_in, const int* in_sizes, int n_in,
                              void* d_out, int out_size, void* d_ws, size_t ws_size,
                              hipStream_t stream) {
    const float* z    = (const float*)d_in[0];   // 16*64*64*64
    const float* emb  = (const float*)d_in[1];   // 1024*64
    const float* prob = (const float*)d_in[2];   // 1024

    float* out        = (float*)d_out;
    float* out_zq     = out;                 // 4194304 floats
    float* out_loss   = out + 4194304;
    float* out_perp   = out + 4194305;
    float* out_newemb = out + 4194306;
    float* out_prob   = out + 4259842;
    float* out_idx    = out + 4260866;

    char* ws = (char*)d_ws;
    unsigned long long* wsrow = (unsigned long long*)(ws + WS_ROW);
    unsigned long long* wscol = (unsigned long long*)(ws + WS_COL);
    unsigned int*       cnts  = (unsigned int*)(ws + WS_CNT);
    double*             lacc  = (double*)(ws + WS_LOSS);
    float*              en2   = (float*)(ws + WS_EN2);
    unsigned int*       lcnt  = (unsigned int*)(ws + WS_LCNT);
    float*              zn2   = (float*)(ws + WS_ZN2);
    unsigned short*     ebh   = (unsigned short*)(ws + WS_EBH);
    unsigned short*     ebl   = (unsigned short*)(ws + WS_EBL);
    unsigned int*       list  = (unsigned int*)(ws + WS_LIST);
    float*              cbm   = (float*)(ws + WS_CBM);

    hipMemsetAsync(d_ws, 0, WS_ZERO, stream);

    hipLaunchKernelGGL(k_prep, dim3(4), dim3(256), 0, stream,
                       emb, en2, (unsigned int*)ebh, (unsigned int*)ebl);
    hipLaunchKernelGGL(k_mfma, dim3(512), dim3(512), 0, stream,
                       z, ebh, ebl, zn2, en2, cbm, wsrow, lcnt, list);
    hipLaunchKernelGGL(k_rescore, dim3(5120), dim3(256), 0, stream,
                       z, emb, zn2, en2, cbm, list, lcnt, wscol, wsrow);
    hipLaunchKernelGGL(k_tokens, dim3(1024), dim3(256), 0, stream,
                       z, emb, wsrow, cnts, lacc, out_zq, out_idx);
    hipLaunchKernelGGL(k_tail, dim3(64), dim3(1024), 0, stream,
                       z, emb, prob, wscol, cnts, lacc,
                       out_newemb, out_loss, out_perp, out_prob);
}

// Round 17
// 201.182 us; speedup vs baseline: 1.5617x; 1.0251x over previous
//
#include <hip/hip_runtime.h>

// VectorQuantiser forward, MI355X fp32.
// N=65536 tokens (16x64x64, channel dim 64 strided by 4096), K=1024 codes, D=64.
//
// Round 19, on the 206.2us round-18 base (best). k_mfma is the only kernel in
// top-5 (59.7us); everything else <58.6 + launch gaps. Three additive cuts:
//  1. k_mfma: 3 independent 2-deep MFMA chains (the round-9/10/11-validated
//     combine fadd(fadd(ahh,ahl),alh)). Round-12's 4-deep merged chain has a
//     2x longer serial critical path -- exposed at MfmaUtil 17%, 4 waves/SIMD.
//  2. memset dispatch DELETED: k_mfma plain-stores wsrow=0 for uncertified
//     tokens (certified already plain-store keys), so wsrow needs no
//     pre-zero; the remaining 16KB (wscol/cnts/loss/lcnt -- NOT en2, which
//     prep blocks 0-3 write concurrently) is zeroed by a 5th k_prep block.
//  3. k_tokens: e-row gather via 4x float4 (was 16 scalar gathers) -- same
//     bytes/values, 4x fewer TA transactions on the random-row path.
// All exact fp paths verbatim; absmax must stay 1.525879e-05.

#define MARGIN 2e-4f
#define CERT   2e-4f

// ---- ws layout (bytes) ----
#define WS_ROW   0         // u64 wsrow[65536]
#define WS_COL   524288    // u64 wscol[1024]
#define WS_CNT   532480    // u32 counts[1024]
#define WS_LOSS  536576    // double loss_acc
#define WS_EN2   536592    // float en2[1024]
#define WS_LCNT  540688    // u32 lcnt
#define WS_ZN2   541696    // float zn2[65536]            (256KB)
#define WS_EBH   803840    // u16 ebf_hi[1024*64]         (128KB)
#define WS_EBL   934912    // u16 ebf_lo[1024*64]         (128KB)
#define WS_LIST  1065984   // u32 list[65536]             (256KB)
#define WS_CBM   1328128   // f32 colbm[1024][512]        (2MB)
#define WS_BYTES 3425280

typedef __attribute__((ext_vector_type(8))) short short8v;
typedef __attribute__((ext_vector_type(4))) float f32x4;

__device__ __forceinline__ unsigned int f32_ord(float x) {
    unsigned int b = __float_as_uint(x);
    return (b & 0x80000000u) ? ~b : (b | 0x80000000u);
}
__device__ __forceinline__ float ord_f32(unsigned int u) {  // exact inverse
    unsigned int b = (u & 0x80000000u) ? (u & 0x7FFFFFFFu) : ~u;
    return __uint_as_float(b);
}

__device__ __forceinline__ unsigned short f2bf(float f) {  // RNE fp32->bf16
    unsigned int u = __float_as_uint(f);
    return (unsigned short)((u + 0x7FFFu + ((u >> 16) & 1u)) >> 16);
}
__device__ __forceinline__ float bf2f(unsigned short h) {
    return __uint_as_float((unsigned int)h << 16);
}

// numpy pairwise sum of squares over 64 values (verbatim from passing code).
template <typename F>
__device__ __forceinline__ float np_pairwise64_sq(F get) {
    float r[8];
#pragma unroll
    for (int j = 0; j < 8; ++j) {
        float v = get(j);
        r[j] = __fmul_rn(v, v);
    }
#pragma unroll
    for (int i = 8; i < 64; i += 8) {
#pragma unroll
        for (int j = 0; j < 8; ++j) {
            float v = get(i + j);
            r[j] = __fadd_rn(r[j], __fmul_rn(v, v));
        }
    }
    return __fadd_rn(__fadd_rn(__fadd_rn(r[0], r[1]), __fadd_rn(r[2], r[3])),
                     __fadd_rn(__fadd_rn(r[4], r[5]), __fadd_rn(r[6], r[7])));
}

// ---- K0: e-prep (blocks 0..3) + ws zeroing (block 4) ----
__global__ __launch_bounds__(256) void k_prep(
    const float* __restrict__ emb, float* __restrict__ en2,
    unsigned int* __restrict__ ebh32, unsigned int* __restrict__ ebl32,
    unsigned int* __restrict__ wszero /* = ws base as u32 */) {
    const int t = threadIdx.x;
    if (blockIdx.x < 4) {
        const int k = blockIdx.x * 256 + t;
        const float* a = emb + (size_t)k * 64;
        float ar[64];
#pragma unroll
        for (int i = 0; i < 64; ++i) ar[i] = a[i];
        en2[k] = np_pairwise64_sq([&](int i) { return ar[i]; });
#pragma unroll
        for (int wd = 0; wd < 32; ++wd) {
            float e0 = ar[2 * wd], e1 = ar[2 * wd + 1];
            unsigned short h0 = f2bf(e0), h1 = f2bf(e1);
            ebh32[k * 32 + wd] = (unsigned int)h0 | ((unsigned int)h1 << 16);
            unsigned short l0 = f2bf(__fsub_rn(e0, bf2f(h0)));
            unsigned short l1 = f2bf(__fsub_rn(e1, bf2f(h1)));
            ebl32[k * 32 + wd] = (unsigned int)l0 | ((unsigned int)l1 << 16);
        }
    } else {
        // zero wscol[1024] u64 + cnts[1024] u32 + loss_acc double + lcnt u32.
        // (wsrow no longer needs zeroing: k_mfma stores every slot. en2 is
        //  NOT touched -- blocks 0..3 write it concurrently.)
        for (unsigned int i = t; i < 3072; i += 256)        // [WS_COL, WS_LOSS)
            wszero[(WS_COL >> 2) + i] = 0u;
        if (t < 2) wszero[(WS_LOSS >> 2) + t] = 0u;         // loss_acc
        if (t == 0) wszero[WS_LCNT >> 2] = 0u;              // lcnt
    }
}

// ---- K1: fused z-prep + s~ via bf16 MFMA + top-2 certification ----
// Main loop = round-18 but with 3 independent 2-deep MFMA chains (validated
// combine from rounds 9-11) and wsrow=0 plain store for uncertified tokens.
__global__ __launch_bounds__(512, 2) void k_mfma(
    const float* __restrict__ z,
    const unsigned short* __restrict__ ebh, const unsigned short* __restrict__ ebl,
    float* __restrict__ zn2, const float* __restrict__ en2,
    float* __restrict__ cbm, unsigned long long* __restrict__ wsrow,
    unsigned int* __restrict__ lcnt, unsigned int* __restrict__ list) {
    const int t = threadIdx.x, l = t & 63, w = t >> 6;
    const int n0 = blockIdx.x * 128;
    const int tw = n0 + w * 16;
    const int lm = l & 15, kg = l >> 4;
    const int b   = n0 >> 12;
    const int hw0 = n0 & 4095;

    __shared__ __align__(16) unsigned char smem[45056];
    unsigned int* eh   = (unsigned int*)(smem);            // [2][64*36]
    unsigned int* el   = (unsigned int*)(smem + 18432);    // [2][64*36]
    float*        en2l = (float*)(smem + 36864);           // [1024]
    unsigned int* cmU  = (unsigned int*)(smem + 40960);    // [1024]
    float*        zl   = (float*)(smem);                   // [64][129] prologue
    float*        zntmp= (float*)(smem + 36864);           // [128]     prologue
    // epilogue carve (overlays dead e-staging region):
    int*          bcnt  = (int*)(smem);                    // [1]
    unsigned int* bbase = (unsigned int*)(smem + 4);       // [1]
    unsigned int* blist = (unsigned int*)(smem + 8);       // [128]

    // --- prologue phase 1: global z -> LDS transpose (coalesced) ---
    const float* zsrc = z + (size_t)b * 262144 + hw0;
#pragma unroll
    for (int it = 0; it < 16; ++it) {
        int idx = it * 512 + t;
        int c = idx >> 7, tok = idx & 127;
        zl[c * 129 + tok] = zsrc[(size_t)c * 4096 + tok];
    }
    __syncthreads();

    // --- prologue phase 2: zn2 (verbatim chain) + fragment assembly ---
    if (t < 128) {
        float v = np_pairwise64_sq([&](int i) { return zl[i * 129 + t]; });
        zn2[n0 + t] = v;
        zntmp[t] = v;
    }
    const int tokA = w * 16 + lm;   // block-local token of this thread's A-frag
    short8v ah0, ah1, al0, al1;
#pragma unroll
    for (int j = 0; j < 8; ++j) {
        float z0 = zl[(kg * 8 + j) * 129 + tokA];
        float z1 = zl[(32 + kg * 8 + j) * 129 + tokA];
        unsigned short h0 = f2bf(z0);
        unsigned short h1 = f2bf(z1);
        ah0[j] = (short)h0;
        ah1[j] = (short)h1;
        al0[j] = (short)f2bf(__fsub_rn(z0, bf2f(h0)));
        al1[j] = (short)f2bf(__fsub_rn(z1, bf2f(h1)));
    }
    __syncthreads();

    // --- prologue phase 3: read zn2 for this thread's C/D rows ---
    float nzn2[4];
#pragma unroll
    for (int j = 0; j < 4; ++j) nzn2[j] = -zntmp[w * 16 + kg * 4 + j];
    __syncthreads();

    // --- prologue phase 4: init en2l/cmU, stage e group 0 ---
    for (int i = t; i < 1024; i += 512) { en2l[i] = en2[i]; cmU[i] = 0u; }
    const uint4* EH4 = reinterpret_cast<const uint4*>(ebh);
    const uint4* EL4 = reinterpret_cast<const uint4*>(ebl);
    const int scode = t >> 3;
    const int sword = (t & 7) ^ (scode & 7);
    const int swd   = sword * 4;
    const int sidx  = scode * 8 + sword;
    {
        uint4 hv = EH4[sidx], lv = EL4[sidx];
        *reinterpret_cast<uint4*>(&eh[0 * 2304 + scode * 36 + swd]) = hv;
        *reinterpret_cast<uint4*>(&el[0 * 2304 + scode * 36 + swd]) = lv;
    }

    float v1[4] = {-3.4e38f, -3.4e38f, -3.4e38f, -3.4e38f};
    float v2[4] = {-3.4e38f, -3.4e38f, -3.4e38f, -3.4e38f};
    int   c1[4] = {0, 0, 0, 0};

    __syncthreads();

    for (int g = 0; g < 16; ++g) {
        const int buf = g & 1;
        const bool pf = (g < 15);
        uint4 hv, lv;
        if (pf) {   // issue next group's loads early; write AFTER compute
            hv = EH4[(g + 1) * 512 + sidx];
            lv = EL4[(g + 1) * 512 + sidx];
        }

#pragma unroll
        for (int sc = 0; sc < 4; ++sc) {
            const int cl = sc * 16 + lm;
            const short8v bh0 = *reinterpret_cast<const short8v*>(&eh[buf * 2304 + cl * 36 + kg * 4]);
            const short8v bh1 = *reinterpret_cast<const short8v*>(&eh[buf * 2304 + cl * 36 + 16 + kg * 4]);
            const short8v bl0 = *reinterpret_cast<const short8v*>(&el[buf * 2304 + cl * 36 + kg * 4]);
            const short8v bl1 = *reinterpret_cast<const short8v*>(&el[buf * 2304 + cl * 36 + 16 + kg * 4]);

            // 3 independent 2-deep chains (round-9/10/11-validated form):
            f32x4 a1 = {0.f, 0.f, 0.f, 0.f};   // hh
            f32x4 a2 = {0.f, 0.f, 0.f, 0.f};   // hl
            f32x4 a3 = {0.f, 0.f, 0.f, 0.f};   // lh
            __builtin_amdgcn_s_setprio(1);
            a1 = __builtin_amdgcn_mfma_f32_16x16x32_bf16(ah0, bh0, a1, 0, 0, 0);
            a2 = __builtin_amdgcn_mfma_f32_16x16x32_bf16(ah0, bl0, a2, 0, 0, 0);
            a3 = __builtin_amdgcn_mfma_f32_16x16x32_bf16(al0, bh0, a3, 0, 0, 0);
            a1 = __builtin_amdgcn_mfma_f32_16x16x32_bf16(ah1, bh1, a1, 0, 0, 0);
            a2 = __builtin_amdgcn_mfma_f32_16x16x32_bf16(ah1, bl1, a2, 0, 0, 0);
            a3 = __builtin_amdgcn_mfma_f32_16x16x32_bf16(al1, bh1, a3, 0, 0, 0);
            __builtin_amdgcn_s_setprio(0);

            const int code = g * 64 + cl;
            const float en2v = en2l[code];
            float cm = -3.4e38f;
#pragma unroll
            for (int j = 0; j < 4; ++j) {
                float acc  = __fadd_rn(__fadd_rn(a1[j], a2[j]), a3[j]);
                float base = __fsub_rn(nzn2[j], en2v);
                float s    = fmaf(2.0f, acc, base);
                // top-2, min/max form (identical values to the branchy version)
                bool gt = s > v1[j];
                v2[j] = fmaxf(fminf(s, v1[j]), v2[j]);
                v1[j] = fmaxf(v1[j], s);
                c1[j] = gt ? code : c1[j];
                cm = fmaxf(cm, s);
            }
            cm = fmaxf(cm, __shfl_xor(cm, 16, 64));
            cm = fmaxf(cm, __shfl_xor(cm, 32, 64));
            if (l < 16) atomicMax(&cmU[code], f32_ord(cm));
        }

        if (pf) {
            *reinterpret_cast<uint4*>(&eh[(buf ^ 1) * 2304 + scode * 36 + swd]) = hv;
            *reinterpret_cast<uint4*>(&el[(buf ^ 1) * 2304 + scode * 36 + swd]) = lv;
        }
        __syncthreads();
    }

    // ---- row finalize: merge top-2, certify; uncertified -> 0 + LDS blist --
    if (t == 0) *bcnt = 0;
    __syncthreads();
#pragma unroll
    for (int j = 0; j < 4; ++j) {
        unsigned long long key =
            ((unsigned long long)f32_ord(v1[j]) << 32) |
            (unsigned long long)(unsigned int)(~(unsigned int)c1[j]);
        float w2 = v2[j];
#pragma unroll
        for (int m = 1; m < 16; m <<= 1) {
            unsigned long long ok = __shfl_xor(key, m, 64);
            float ov2 = __shfl_xor(w2, m, 64);
            unsigned long long lk = (key < ok) ? key : ok;   // losing top1
            float lv2 = ord_f32((unsigned int)(lk >> 32));
            w2 = fmaxf(fmaxf(w2, ov2), lv2);
            key = (key > ok) ? key : ok;                      // ties: smaller c
        }
        if (lm == 0) {
            const int tn = tw + kg * 4 + j;
            float v1m = ord_f32((unsigned int)(key >> 32));
            if (__fsub_rn(v1m, w2) > CERT) {
                wsrow[tn] = key;      // certified: provably exact argmax index
            } else {
                wsrow[tn] = 0ull;     // rescore will atomicMax into this
                int p = atomicAdd(bcnt, 1);
                blist[p] = (unsigned int)tn;
            }
        }
    }
    __syncthreads();
    if (t == 0 && *bcnt > 0) *bbase = atomicAdd(lcnt, (unsigned int)*bcnt);
    __syncthreads();
    {
        const int cb2 = *bcnt;
        for (int i = t; i < cb2; i += 512) list[*bbase + i] = blist[i];
    }

    for (int code = t; code < 1024; code += 512)
        cbm[(size_t)code * 512 + blockIdx.x] = ord_f32(cmU[code]);
}

// ---- K2: merged exact rescore. Col: blocks 0..1023 (verbatim body).
// Row: blocks 1024..5119 = 64 x-slots x 64 partitions of 16 codes.
__global__ __launch_bounds__(256) void k_rescore(
    const float* __restrict__ z, const float* __restrict__ emb,
    const float* __restrict__ zn2, const float* __restrict__ en2,
    const float* __restrict__ cbm,
    const unsigned int* __restrict__ list, const unsigned int* __restrict__ lcnt,
    unsigned long long* __restrict__ wscol,
    unsigned long long* __restrict__ wsrow) {
    const int t = threadIdx.x;
    if (blockIdx.x < 1024) {
        // -- column rescore: block per code --
        const int k = blockIdx.x;
        __shared__ float red[256];
        __shared__ int   hlist[512];
        __shared__ int   hcnt;
        float a  = cbm[(size_t)k * 512 + t];
        float b2 = cbm[(size_t)k * 512 + 256 + t];
        red[t] = fmaxf(a, b2);
        if (t == 0) hcnt = 0;
        __syncthreads();
        for (int st = 128; st; st >>= 1) {
            if (t < st) red[t] = fmaxf(red[t], red[t + st]);
            __syncthreads();
        }
        const float thr = red[0] - MARGIN;
        if (a >= thr)  { int p = atomicAdd(&hcnt, 1); hlist[p] = t; }
        if (b2 >= thr) { int p = atomicAdd(&hcnt, 1); hlist[p] = t + 256; }
        __syncthreads();
        const int hc = hcnt;
        const float en2k = en2[k];
        const float4* ek = reinterpret_cast<const float4*>(emb + (size_t)k * 64);

        for (int h = 0; h < hc; ++h) {
            const int g = hlist[h];
            if (t < 128) {
                const int n = g * 128 + t;
                const int b = n >> 12, hw = n & 4095;
                const float* zp = z + (size_t)b * 262144 + hw;
                float c0 = 0.f, c1 = 0.f, c2 = 0.f, c3 = 0.f;
#pragma unroll
                for (int j = 0; j < 16; ++j) {
                    float4 e = ek[j];
                    c0 = fmaf(e.x, zp[(size_t)(4 * j + 0) * 4096], c0);
                    c1 = fmaf(e.y, zp[(size_t)(4 * j + 1) * 4096], c1);
                    c2 = fmaf(e.z, zp[(size_t)(4 * j + 2) * 4096], c2);
                    c3 = fmaf(e.w, zp[(size_t)(4 * j + 3) * 4096], c3);
                }
                float dot = (c0 + c1) + (c2 + c3);
                float d = __fadd_rn(__fsub_rn(-zn2[n], en2k), 2.0f * dot);
                unsigned long long key =
                    ((unsigned long long)f32_ord(d) << 32) |
                    (unsigned long long)(unsigned int)(~(unsigned int)n);
#pragma unroll
                for (int m = 1; m < 64; m <<= 1) {
                    unsigned long long o = __shfl_xor(key, m, 64);
                    if (o > key) key = o;    // ties: larger key = smaller n
                }
                if ((t & 63) == 0) atomicMax(&wscol[k], key);
            }
        }
    } else {
        // -- row rescore: 64 partitions x 16 codes, thread-per-candidate --
        const int bid2 = blockIdx.x - 1024;        // [0, 4096)
        const int k0 = (bid2 & 63) * 16;           // 16-code partition
        const int xs = bid2 >> 6;                  // x-slot [0, 64)
        const unsigned int cnt = *lcnt;
        const float4* E4 = reinterpret_cast<const float4*>(emb);
        for (unsigned int i = (unsigned int)xs * 256 + t; i < cnt;
             i += 64 * 256) {
            const int n = (int)list[i];
            const int b = n >> 12, hw = n & 4095;
            const float* zp = z + (size_t)b * 262144 + hw;
            const float nz = -zn2[n];
            unsigned long long best = 0ull;
            for (int kk = 0; kk < 16; ++kk) {
                const int k = k0 + kk;               // wave-uniform -> s_load
                const float4* ek = E4 + (size_t)k * 16;
                float c0 = 0.f, c1 = 0.f, c2 = 0.f, c3 = 0.f;
#pragma unroll
                for (int j = 0; j < 16; ++j) {
                    float4 e = ek[j];
                    c0 = fmaf(e.x, zp[(size_t)(4 * j + 0) * 4096], c0);
                    c1 = fmaf(e.y, zp[(size_t)(4 * j + 1) * 4096], c1);
                    c2 = fmaf(e.z, zp[(size_t)(4 * j + 2) * 4096], c2);
                    c3 = fmaf(e.w, zp[(size_t)(4 * j + 3) * 4096], c3);
                }
                float dot = (c0 + c1) + (c2 + c3);
                float d = __fadd_rn(__fsub_rn(nz, en2[k]), 2.0f * dot);
                unsigned long long key =
                    ((unsigned long long)f32_ord(d) << 32) |
                    (unsigned long long)(unsigned int)(~(unsigned int)k);
                if (key > best) best = key;   // ties: larger key = smaller k
            }
            atomicMax(&wsrow[n], best);
        }
    }
}

// ---- K3: per-token outputs, 4-way channel split (1024 blocks) ----
__global__ __launch_bounds__(256) void k_tokens(
    const float* __restrict__ z, const float* __restrict__ emb,
    const unsigned long long* __restrict__ wsrow,
    unsigned int* __restrict__ counts, double* __restrict__ loss_acc,
    float* __restrict__ out_zq, float* __restrict__ out_idx) {
    const int t    = threadIdx.x;
    const int lane = t & 63;
    const int q    = t >> 6;
    const int n    = blockIdx.x * 64 + lane;
    const int b    = n >> 12;
    const int hw   = n & 4095;

    unsigned long long key = wsrow[n];
    int idx = (int)(~(unsigned int)(key & 0xFFFFFFFFull));
    if (q == 0) {
        out_idx[n] = (float)idx;
        atomicAdd(&counts[idx], 1u);
    }

    const float* zp = z + (size_t)b * 262144 + hw;
    float*       op = out_zq + (size_t)b * 262144 + hw;

    // e quarter via 4x float4 (same bytes/values; 4x fewer gather insts)
    const float4* ep4 =
        reinterpret_cast<const float4*>(emb + (size_t)idx * 64 + q * 16);
    float4 e4[4];
#pragma unroll
    for (int i = 0; i < 4; ++i) e4[i] = ep4[i];
    const float* er = reinterpret_cast<const float*>(e4);

    double ls = 0.0;
#pragma unroll
    for (int c = 0; c < 16; ++c) {
        const int ch = q * 16 + c;
        float zc   = zp[(size_t)ch * 4096];
        float eq   = er[c];
        float diff = __fsub_rn(eq, zc);              // fl(z_q - zc)
        float sq   = __fmul_rn(diff, diff);
        ls += (double)sq;
        op[(size_t)ch * 4096] = __fadd_rn(zc, diff); // zc + fl(z_q - zc)
    }

    __shared__ double sred[256];
    sred[q * 64 + lane] = ls;
    __syncthreads();
    if (t < 64) {
        sred[t] = (sred[t] + sred[64 + t]) + (sred[128 + t] + sred[192 + t]);
    }
    __syncthreads();
    for (int st = 32; st; st >>= 1) {
        if (t < st) sred[t] += sred[t + st];
        __syncthreads();
    }
    if (t == 0) atomicAdd(loss_acc, sred[0]);
}

// ---- K4: tail — new embedding + scalars (unchanged) ----
__global__ __launch_bounds__(1024) void k_tail(
    const float* __restrict__ z, const float* __restrict__ emb,
    const float* __restrict__ embed_prob,
    const unsigned long long* __restrict__ wscol,
    const unsigned int* __restrict__ counts,
    const double* __restrict__ loss_acc,
    float* __restrict__ out_newemb, float* __restrict__ out_loss,
    float* __restrict__ out_perp, float* __restrict__ out_prob) {
    const int k = blockIdx.x * 16 + (threadIdx.x >> 6);
    const int c = threadIdx.x & 63;

    float avg  = (float)counts[k] * (1.0f / 65536.0f);
    float pnew = __fadd_rn(__fmul_rn(embed_prob[k], 0.99f),
                           __fmul_rn(0.01f, avg));
    float tt = __fdiv_rn(__fmul_rn(__fmul_rn(pnew, 1024.0f), 10.0f), 0.01f);
    float dk = expf(__fsub_rn(-tt, 1e-3f));
    float omd = __fsub_rn(1.0f, dk);

    unsigned long long ck = wscol[k];
    int cn  = (int)(~(unsigned int)(ck & 0xFFFFFFFFull));
    int cb  = cn >> 12;
    int chw = cn & 4095;

    float rf = z[(size_t)cb * 262144 + (size_t)c * 4096 + chw];
    float e  = emb[(size_t)k * 64 + c];
    out_newemb[(size_t)k * 64 + c] =
        __fadd_rn(__fmul_rn(e, omd), __fmul_rn(rf, dk));

    if (blockIdx.x == 0) {
        const int q = threadIdx.x;

        float avg2  = (float)counts[q] * (1.0f / 65536.0f);
        float pnew2 = __fadd_rn(__fmul_rn(embed_prob[q], 0.99f),
                                __fmul_rn(0.01f, avg2));
        out_prob[q] = pnew2;

        float term = __fmul_rn(avg2, logf(__fadd_rn(avg2, 1e-10f)));
        __shared__ double red[1024];
        red[q] = (double)term;
        __syncthreads();
        for (int st = 512; st; st >>= 1) {
            if (q < st) red[q] += red[q + st];
            __syncthreads();
        }
        if (q == 0) {
            float s32 = (float)red[0];
            out_perp[0] = expf(-s32);
            double lm = loss_acc[0] / 4194304.0;
            float  m  = (float)lm;
            out_loss[0] = __fadd_rn(__fmul_rn(0.25f, m), m);  // BETA*m + m
        }
    }
}

extern "C" void kernel_launch(void* const* d_in, const int* in_sizes, int n_in,
                              void* d_out, int out_size, void* d_ws, size_t ws_size,
                              hipStream_t stream) {
    const float* z    = (const float*)d_in[0];   // 16*64*64*64
    const float* emb  = (const float*)d_in[1];   // 1024*64
    const float* prob = (const float*)d_in[2];   // 1024

    float* out        = (float*)d_out;
    float* out_zq     = out;                 // 4194304 floats
    float* out_loss   = out + 4194304;
    float* out_perp   = out + 4194305;
    float* out_newemb = out + 4194306;
    float* out_prob   = out + 4259842;
    float* out_idx    = out + 4260866;

    char* ws = (char*)d_ws;
    unsigned long long* wsrow = (unsigned long long*)(ws + WS_ROW);
    unsigned long long* wscol = (unsigned long long*)(ws + WS_COL);
    unsigned int*       cnts  = (unsigned int*)(ws + WS_CNT);
    double*             lacc  = (double*)(ws + WS_LOSS);
    float*              en2   = (float*)(ws + WS_EN2);
    unsigned int*       lcnt  = (unsigned int*)(ws + WS_LCNT);
    float*              zn2   = (float*)(ws + WS_ZN2);
    unsigned short*     ebh   = (unsigned short*)(ws + WS_EBH);
    unsigned short*     ebl   = (unsigned short*)(ws + WS_EBL);
    unsigned int*       list  = (unsigned int*)(ws + WS_LIST);
    float*              cbm   = (float*)(ws + WS_CBM);

    hipLaunchKernelGGL(k_prep, dim3(5), dim3(256), 0, stream,
                       emb, en2, (unsigned int*)ebh, (unsigned int*)ebl,
                       (unsigned int*)ws);
    hipLaunchKernelGGL(k_mfma, dim3(512), dim3(512), 0, stream,
                       z, ebh, ebl, zn2, en2, cbm, wsrow, lcnt, list);
    hipLaunchKernelGGL(k_rescore, dim3(5120), dim3(256), 0, stream,
                       z, emb, zn2, en2, cbm, list, lcnt, wscol, wsrow);
    hipLaunchKernelGGL(k_tokens, dim3(1024), dim3(256), 0, stream,
                       z, emb, wsrow, cnts, lacc, out_zq, out_idx);
    hipLaunchKernelGGL(k_tail, dim3(64), dim3(1024), 0, stream,
                       z, emb, prob, wscol, cnts, lacc,
                       out_newemb, out_loss, out_perp, out_prob);
}